// Round 8
// baseline (312.689 us; speedup 1.0000x reference)
//
#include <hip/hip_runtime.h>
#include <hip/hip_bf16.h>

#define NN  16
#define WT  256
#define TT  2048
#define DIM 256
#define TBT 8      // t-values per block in score kernels

typedef __attribute__((ext_vector_type(8))) short short8_t;  // 8 bf16 (4 VGPRs)
typedef __attribute__((ext_vector_type(4))) float f32x4;     // MFMA acc

__device__ __forceinline__ float fast_rcp(float x){ return __builtin_amdgcn_rcpf(x); }

// silu_f is numerically self-saturating: x>20 -> exp(-x)=0 -> rcp(1)=1 -> x (exact);
// x<-20 -> exp(-x)=inf -> rcp(inf)=0 -> 0 (exact).
__device__ __forceinline__ float silu_f(float x){
    return x * fast_rcp(1.0f + __expf(-x));
}

__device__ __forceinline__ unsigned short f2bf(float x){
    union { float f; unsigned u; } v; v.f = x;
    unsigned r = v.u + 0x7FFFu + ((v.u >> 16) & 1u);   // round-to-nearest-even
    return (unsigned short)(r >> 16);
}

__device__ __forceinline__ void fma4(float4& a, float s, const float4& f){
    a.x = fmaf(s, f.x, a.x); a.y = fmaf(s, f.y, a.y);
    a.z = fmaf(s, f.z, a.z); a.w = fmaf(s, f.w, a.w);
}

// ------- Kernel I: zero T1N (atomicMax accumulator), 16 floats -------
__global__ void init_k(float* __restrict__ T1N)
{
    if (threadIdx.x < NN) T1N[threadIdx.x] = 0.0f;
}

// ------- Kernel B: cumsum + conv(3,256->8)+BN+SiLU -> v1/v2, + R8 linear precompute -------
// R8 additions (cost ~100 cycles tail per block): per (n,w) the asymptotic (t large)
// saturation set is {i: u_i>0} -- u is GLOBAL (16 values).  So hB_j = sum_{u>0} u_i W_ij
// is a global constant vector, hA_j = b2_j + sum_{u>0} v_i W_ij is per-(n,w).
// Beyond T1N[n] = max_i,w crossing of x_i (+1 margin), h_j = hA_j + hB_j*t EXACTLY.
// u_i==0 -> crossing INF -> T1N=INF -> downstream never uses linear path (safe).
__global__ __launch_bounds__(256) void prep_k(
    const float* __restrict__ dur, const float* __restrict__ feat,
    const float* __restrict__ c1w, const float* __restrict__ c1b,
    const float* __restrict__ g1,  const float* __restrict__ be1,
    const float* __restrict__ m1,  const float* __restrict__ vv1,
    const float* __restrict__ c2w, const float* __restrict__ c2b,
    const float* __restrict__ g2,  const float* __restrict__ be2,
    const float* __restrict__ m2,  const float* __restrict__ vv2,
    const float* __restrict__ sb1w1, const float* __restrict__ sb1b1,
    const float* __restrict__ sb2w1, const float* __restrict__ sb2b1,
    const float* __restrict__ sb2w2, const float* __restrict__ sb2b2,
    float* __restrict__ v1o, float* __restrict__ v2o,
    float* __restrict__ hAo, float* __restrict__ hBo, float* __restrict__ T1No)
{
    int w = blockIdx.x, n = blockIdx.y;
    int tid = threadIdx.x;              // channel c

    // ---- in-block inclusive scan of durations for this n ----
    __shared__ float sdur[WT];
    sdur[tid] = dur[n*WT + tid];
    __syncthreads();
    for (int off = 1; off < WT; off <<= 1){
        float v = (tid >= off) ? sdur[tid-off] : 0.0f;
        __syncthreads();
        sdur[tid] += v;
        __syncthreads();
    }
    float end   = sdur[w];              // broadcast read
    float start = end - dur[n*WT + w];  // uniform scalar load

    const float* fb = feat + (size_t)(n*WT)*DIM;
    float fm = (w > 0)    ? fb[(size_t)(w-1)*DIM + tid] : 0.0f;
    float f0 =              fb[(size_t) w   *DIM + tid];
    float fp = (w < WT-1) ? fb[(size_t)(w+1)*DIM + tid] : 0.0f;

    float pl[8], pr[8];
    #pragma unroll
    for (int o = 0; o < 8; o++){
        const float* wp = c1w + (size_t)(o*DIM + tid)*3;
        pl[o] = fmaf(fm, wp[0], fmaf(f0, wp[1], fp*wp[2]));
        const float* wq = c2w + (size_t)(o*DIM + tid)*3;
        pr[o] = fmaf(fm, wq[0], fmaf(f0, wq[1], fp*wq[2]));
    }
    #pragma unroll
    for (int o = 0; o < 8; o++){
        #pragma unroll
        for (int off = 32; off; off >>= 1){
            pl[o] += __shfl_xor(pl[o], off);
            pr[o] += __shfl_xor(pr[o], off);
        }
    }
    __shared__ float sws[4][16];
    int wave = tid >> 6, lane = tid & 63;
    if (lane == 0){
        #pragma unroll
        for (int o = 0; o < 8; o++){ sws[wave][o] = pl[o]; sws[wave][8+o] = pr[o]; }
    }
    __syncthreads();
    __shared__ float slr[16];   // [0..7]=left(SiLU'd), [8..15]=right
    if (tid < 16){
        float s = sws[0][tid] + sws[1][tid] + sws[2][tid] + sws[3][tid];
        int o = tid & 7; bool isr = tid >= 8;
        float bias = isr ? c2b[o] : c1b[o];
        float mm   = isr ? m2[o]  : m1[o];
        float vv   = isr ? vv2[o] : vv1[o];
        float gg   = isr ? g2[o]  : g1[o];
        float bb   = isr ? be2[o] : be1[o];
        float y = s + bias;
        y = (y - mm) * rsqrtf(vv + 1e-5f);
        y = y * gg + bb;
        slr[tid] = silu_f(y);
    }
    __syncthreads();

    __shared__ float sv[16], su[16], stp[16];
    if (tid < 16){
        int j = tid;
        float acc = sb2b1[j] - start*sb2w1[j] + end*sb2w1[16 + j];
        #pragma unroll
        for (int o = 0; o < 8; o++) acc = fmaf(slr[8+o], sb2w1[(2+o)*16 + j], acc);
        v2o[(size_t)(n*WT + w)*16 + j] = acc;
        // R8: i-level crossing
        float u = sb2w1[j] - sb2w1[16 + j];
        sv[j] = acc; su[j] = u;
        float tp;
        if (u > 0.0f)      tp = (20.0f - acc) / u + 1.0f;
        else if (u < 0.0f) tp = (-20.0f - acc) / u + 1.0f;
        else               tp = 3.0e38f;   // never saturates -> never linear
        stp[j] = tp;
    } else if (tid < 18){
        int p = tid - 16;
        float acc = sb1b1[p] - start*sb1w1[p] + end*sb1w1[2 + p];
        #pragma unroll
        for (int o = 0; o < 8; o++) acc = fmaf(slr[o], sb1w1[(2+o)*2 + p], acc);
        v1o[(size_t)(n*WT + w)*2 + p] = acc;
    }
    __syncthreads();
    if (hAo && tid < 16){
        int j = tid;
        float hA = sb2b2[j], hB = 0.0f;
        #pragma unroll
        for (int i = 0; i < 16; i++){
            if (su[i] > 0.0f){
                float wv = sb2w2[i*16 + j];
                hA = fmaf(sv[i], wv, hA);
                hB = fmaf(su[i], wv, hB);
            }
        }
        hAo[((size_t)(n*WT + w))*16 + j] = hA;
        if (w == 0 && n == 0) hBo[j] = hB;   // global constant, write once
    }
    if (hAo && tid == 0){
        float tmax = 0.0f;
        #pragma unroll
        for (int i = 0; i < 16; i++) tmax = fmaxf(tmax, stp[i]);
        atomicMax((unsigned int*)&T1No[n], __float_as_uint(tmax));  // tmax>=0: bits ordered
    }
}

// ------- Kernel B2: pack feat into B-fragment bf16 layout [n][w/32][d][w%32] -------
__global__ __launch_bounds__(256) void featpack_k(const float* __restrict__ feat,
                                                  unsigned short* __restrict__ featP)
{
    int kb = blockIdx.x, n = blockIdx.y;   // kb = 0..7 (k-block of 32 w's)
    int d = threadIdx.x;
    const float* fb = feat + (size_t)n*WT*DIM + (size_t)kb*32*DIM + d;
    unsigned short* op = featP + ((size_t)(n*8 + kb)*DIM + d)*32;
    unsigned short buf[32];
    #pragma unroll
    for (int e = 0; e < 32; e++) buf[e] = f2bf(fb[(size_t)e*DIM]);   // coalesced reads
    #pragma unroll
    for (int g = 0; g < 4; g++){
        uint4 u;
        u.x = (unsigned)buf[g*8+0] | ((unsigned)buf[g*8+1] << 16);
        u.y = (unsigned)buf[g*8+2] | ((unsigned)buf[g*8+3] << 16);
        u.z = (unsigned)buf[g*8+4] | ((unsigned)buf[g*8+5] << 16);
        u.w = (unsigned)buf[g*8+6] | ((unsigned)buf[g*8+7] << 16);
        *(uint4*)(op + g*8) = u;
    }
}

// ---------------- Kernel S1: raw scores for the NON-LINEAR region only ----------------
// R8: uniform early-exit when t0 > T1N[n] (all x_i saturated for every w -> S2
// computes scores from hA/hB directly).  Remaining blocks run the R7 tier body.
// S1's duration now directly reads out the non-linear fraction ~ T1N/2048.
__global__ __launch_bounds__(256) void score1_k(
    const float* __restrict__ Tg, const float* __restrict__ v2g,
    const float* __restrict__ sb2w1, const float* __restrict__ sb2w2, const float* __restrict__ sb2b2,
    const float* __restrict__ p2w, const float* __restrict__ p2b,
    const float* __restrict__ T1Ng,
    float* __restrict__ scr)
{
    int n   = blockIdx.y;
    int t0  = blockIdx.x * TBT;
    if ((float)t0 > T1Ng[n]) return;   // block-uniform: S2 handles via linear path
    int tid = threadIdx.x;
    int w   = tid;

    __shared__ float s_w2[16*16];
    __shared__ float s_u2[16], s_b2[16], s_p2w[16];

    s_w2[tid] = sb2w2[tid];
    if (tid < 16){
        s_u2[tid]  = sb2w1[tid] - sb2w1[16 + tid];
        s_b2[tid]  = sb2b2[tid];
        s_p2w[tid] = p2w[tid];
    }
    __syncthreads();   // the ONLY barrier: weight staging

    float v2r[16];
    {
        const float4* vp = (const float4*)(v2g + (size_t)(n*WT + w)*16);
        float4 a = vp[0], b = vp[1], c = vp[2], d = vp[3];
        v2r[0]=a.x; v2r[1]=a.y; v2r[2]=a.z; v2r[3]=a.w;
        v2r[4]=b.x; v2r[5]=b.y; v2r[6]=b.z; v2r[7]=b.w;
        v2r[8]=c.x; v2r[9]=c.y; v2r[10]=c.z; v2r[11]=c.w;
        v2r[12]=d.x; v2r[13]=d.y; v2r[14]=d.z; v2r[15]=d.w;
    }
    float p2bv = p2b[0];
    float tv[TBT];
    #pragma unroll
    for (int ti = 0; ti < TBT; ti++) tv[ti] = Tg[t0 + ti];

    // ---- classify saturation of each a_i over this block's t-window ----
    unsigned mpos = 0u, mneg = 0u;
    #pragma unroll
    for (int i = 0; i < 16; i++){
        float u = s_u2[i], v = v2r[i];
        float xa = fmaf(tv[0],     u, v);
        float xb = fmaf(tv[TBT-1], u, v);
        float lo = fminf(xa, xb), hi = fmaxf(xa, xb);
        if (__all(lo >  20.0f)) mpos |= (1u << i);
        else if (__all(hi < -20.0f)) mneg |= (1u << i);
    }
    unsigned mact = 0xFFFFu & ~(mpos | mneg);

    float scores[TBT];
    if (mact == 0u){
        // -------- all i saturated -> h_j exactly linear in t --------
        float hA[16], hB[16];
        #pragma unroll
        for (int j = 0; j < 16; j++){ hA[j] = s_b2[j]; hB[j] = 0.0f; }
        #pragma unroll
        for (int i = 0; i < 16; i++){
            if (mpos & (1u << i)){          // wave-uniform scalar branch
                float u = s_u2[i], v = v2r[i];
                #pragma unroll
                for (int j = 0; j < 16; j++){
                    float wv = s_w2[i*16 + j];
                    hA[j] = fmaf(v, wv, hA[j]);
                    hB[j] = fmaf(u, wv, hB[j]);
                }
            }
        }
        unsigned jpos = 0u, jact = 0u;
        #pragma unroll
        for (int j = 0; j < 16; j++){
            float h0 = fmaf(tv[0],     hB[j], hA[j]);
            float h7 = fmaf(tv[TBT-1], hB[j], hA[j]);
            float lo = fminf(h0, h7), hi = fmaxf(h0, h7);
            unsigned p  = (unsigned)__all(lo > 20.0f);
            unsigned nn = (unsigned)__all(hi < -20.0f);
            jpos |= p << j;
            jact |= ((p | nn) ^ 1u) << j;
        }
        float SA = p2bv, SB = 0.0f;
        #pragma unroll
        for (int j = 0; j < 16; j++){
            float pw = s_p2w[j] * (float)((jpos >> j) & 1u);
            SA = fmaf(hA[j], pw, SA);
            SB = fmaf(hB[j], pw, SB);
        }
        #pragma unroll
        for (int ti = 0; ti < TBT; ti++) scores[ti] = fmaf(tv[ti], SB, SA);
        #pragma unroll
        for (int j = 0; j < 16; j++){
            if (jact & (1u << j)){
                float pw = s_p2w[j];
                float a = hA[j], b = hB[j];
                #pragma unroll
                for (int ti = 0; ti < TBT; ti++)
                    scores[ti] = fmaf(silu_f(fmaf(tv[ti], b, a)), pw, scores[ti]);
            }
        }
    } else {
        // -------- slow tier: per-pair, skip neg-i, linear pos-i --------
        #pragma unroll
        for (int tp = 0; tp < TBT; tp += 2){
            float h2a[16], h2b[16];
            #pragma unroll
            for (int j = 0; j < 16; j++){ float b = s_b2[j]; h2a[j] = b; h2b[j] = b; }
            #pragma unroll
            for (int i = 0; i < 16; i++){
                if (mneg & (1u << i)) continue;           // a == 0: skip fan-out
                float u = s_u2[i], v = v2r[i];
                float aa = fmaf(tv[tp],   u, v);
                float ab = fmaf(tv[tp+1], u, v);
                if (!(mpos & (1u << i))){                 // not linear-saturated
                    aa = silu_f(aa);
                    ab = silu_f(ab);
                }
                #pragma unroll
                for (int j = 0; j < 16; j++){
                    float wv = s_w2[i*16 + j];
                    h2a[j] = fmaf(aa, wv, h2a[j]);
                    h2b[j] = fmaf(ab, wv, h2b[j]);
                }
            }
            float sa = p2bv, sb = p2bv;
            #pragma unroll
            for (int j = 0; j < 16; j++){
                float pw = s_p2w[j];
                float ha = h2a[j], hb = h2b[j];
                if (__all(fminf(ha, hb) > 20.0f)){
                    sa = fmaf(ha, pw, sa);
                    sb = fmaf(hb, pw, sb);
                } else if (__all(fmaxf(ha, hb) < -20.0f)){
                    // silu(h) ~ 0: no contribution
                } else {
                    sa = fmaf(silu_f(ha), pw, sa);
                    sb = fmaf(silu_f(hb), pw, sb);
                }
            }
            scores[tp] = sa; scores[tp+1] = sb;
        }
    }

    float* sbase = scr + ((size_t)n*TT + t0)*WT + w;
    #pragma unroll
    for (int ti = 0; ti < TBT; ti++) sbase[(size_t)ti*WT] = scores[ti];
}

// ---------------- Kernel S2: softmax + c-path + normalize ----------------
// R8: in the linear region (t0 > T1N[n]) compute scores directly from the
// precomputed hA (per n,w) and hB (global const): endpoint-classify j, fold
// pos-j into SA/SB, silu only active j's.  No fold, no mask build, no scr read.
__global__ __launch_bounds__(256) void score2_k(
    const float* __restrict__ Tg, const float* __restrict__ v1g,
    const float* __restrict__ scr,
    const float* __restrict__ hAg, const float* __restrict__ hBg,
    const float* __restrict__ T1Ng,
    const float* __restrict__ sb1w1, const float* __restrict__ sb1w2, const float* __restrict__ sb1b2,
    const float* __restrict__ p2w, const float* __restrict__ p2b,
    unsigned short* __restrict__ wsm_b, float* __restrict__ wc_g)
{
    int n   = blockIdx.y;
    int t0  = blockIdx.x * TBT;
    int tid = threadIdx.x;
    int w   = tid;
    int lane = tid & 63, wave = tid >> 6;

    __shared__ float s_xa[4][TBT];
    __shared__ float s_xs[4][TBT];
    __shared__ float s_xc0[4][TBT], s_xc1[4][TBT];

    float v1r0, v1r1;
    {
        const float* vp = v1g + (size_t)(n*WT + w)*2;
        v1r0 = vp[0]; v1r1 = vp[1];
    }
    float tv[TBT];
    #pragma unroll
    for (int ti = 0; ti < TBT; ti++) tv[ti] = Tg[t0 + ti];

    float scores[TBT];
    if ((float)t0 > T1Ng[n]){
        // ---- linear region: h_j = hA_j + hB_j*t exactly ----
        float hA[16];
        {
            const float4* hp = (const float4*)(hAg + ((size_t)(n*WT + w))*16);
            float4 a = hp[0], b = hp[1], c = hp[2], d = hp[3];
            hA[0]=a.x; hA[1]=a.y; hA[2]=a.z; hA[3]=a.w;
            hA[4]=b.x; hA[5]=b.y; hA[6]=b.z; hA[7]=b.w;
            hA[8]=c.x; hA[9]=c.y; hA[10]=c.z; hA[11]=c.w;
            hA[12]=d.x; hA[13]=d.y; hA[14]=d.z; hA[15]=d.w;
        }
        float p2bv = p2b[0];
        unsigned jpos = 0u, jact = 0u;
        #pragma unroll
        for (int j = 0; j < 16; j++){
            float hb = hBg[j];                       // uniform -> SGPR
            float h0 = fmaf(tv[0],     hb, hA[j]);
            float h7 = fmaf(tv[TBT-1], hb, hA[j]);
            float lo = fminf(h0, h7), hi = fmaxf(h0, h7);
            unsigned p  = (unsigned)__all(lo > 20.0f);
            unsigned nn = (unsigned)__all(hi < -20.0f);
            jpos |= p << j;
            jact |= ((p | nn) ^ 1u) << j;
        }
        float SA = p2bv, SB = 0.0f;
        #pragma unroll
        for (int j = 0; j < 16; j++){
            float pw = p2w[j] * (float)((jpos >> j) & 1u);
            SA = fmaf(hA[j], pw, SA);
            SB = fmaf(hBg[j], pw, SB);
        }
        #pragma unroll
        for (int ti = 0; ti < TBT; ti++) scores[ti] = fmaf(tv[ti], SB, SA);
        #pragma unroll
        for (int j = 0; j < 16; j++){
            if (jact & (1u << j)){
                float pw = p2w[j];
                float a = hA[j], b = hBg[j];
                #pragma unroll
                for (int ti = 0; ti < TBT; ti++)
                    scores[ti] = fmaf(silu_f(fmaf(tv[ti], b, a)), pw, scores[ti]);
            }
        }
    } else {
        const float* sbase = scr + ((size_t)n*TT + t0)*WT + w;
        #pragma unroll
        for (int ti = 0; ti < TBT; ti++) scores[ti] = sbase[(size_t)ti*WT];
    }

    // ---- c-path (uniform scalars; silu exact at extremes) ----
    float c0r[TBT], c1r[TBT];
    {
        float u10 = sb1w1[0] - sb1w1[2], u11 = sb1w1[1] - sb1w1[3];
        float w00 = sb1w2[0], w01 = sb1w2[1], w10 = sb1w2[2], w11 = sb1w2[3];
        float b0 = sb1b2[0], b1 = sb1b2[1];
        float x0a = fmaf(tv[0], u10, v1r0), x0b = fmaf(tv[TBT-1], u10, v1r0);
        float x1a = fmaf(tv[0], u11, v1r1), x1b = fmaf(tv[TBT-1], u11, v1r1);
        bool p0 = __all(fminf(x0a, x0b) >  20.0f);
        bool n0 = __all(fmaxf(x0a, x0b) < -20.0f);
        bool p1 = __all(fminf(x1a, x1b) >  20.0f);
        bool n1 = __all(fmaxf(x1a, x1b) < -20.0f);
        #pragma unroll
        for (int ti = 0; ti < TBT; ti++){
            float x0 = fmaf(tv[ti], u10, v1r0);
            float x1 = fmaf(tv[ti], u11, v1r1);
            float gl0, gl1;
            if (p0)      gl0 = x0;
            else if (n0) gl0 = 0.0f;
            else         gl0 = silu_f(x0);
            if (p1)      gl1 = x1;
            else if (n1) gl1 = 0.0f;
            else         gl1 = silu_f(x1);
            float y0 = fmaf(gl0, w00, fmaf(gl1, w10, b0));
            float y1 = fmaf(gl0, w01, fmaf(gl1, w11, b1));
            if (__all(fminf(y0, y1) > 20.0f)){
                c0r[ti] = y0; c1r[ti] = y1;
            } else if (__all(fmaxf(y0, y1) < -20.0f)){
                c0r[ti] = 0.0f; c1r[ti] = 0.0f;
            } else {
                c0r[ti] = silu_f(y0); c1r[ti] = silu_f(y1);
            }
        }
    }

    float m[TBT];
    #pragma unroll
    for (int ti = 0; ti < TBT; ti++) m[ti] = scores[ti];
    #pragma unroll
    for (int off = 32; off; off >>= 1){
        #pragma unroll
        for (int ti = 0; ti < TBT; ti++) m[ti] = fmaxf(m[ti], __shfl_xor(m[ti], off));
    }
    if (lane == 0){
        #pragma unroll
        for (int ti = 0; ti < TBT; ti++) s_xa[wave][ti] = m[ti];
    }
    __syncthreads();
    #pragma unroll
    for (int ti = 0; ti < TBT; ti++)
        m[ti] = fmaxf(fmaxf(s_xa[0][ti], s_xa[1][ti]), fmaxf(s_xa[2][ti], s_xa[3][ti]));

    float e[TBT], ps[TBT], pc0[TBT], pc1[TBT];
    #pragma unroll
    for (int ti = 0; ti < TBT; ti++){
        e[ti]   = __expf(scores[ti] - m[ti]);
        ps[ti]  = e[ti];
        pc0[ti] = e[ti] * c0r[ti];
        pc1[ti] = e[ti] * c1r[ti];
    }
    #pragma unroll
    for (int off = 32; off; off >>= 1){
        #pragma unroll
        for (int ti = 0; ti < TBT; ti++){
            ps[ti]  += __shfl_xor(ps[ti],  off);
            pc0[ti] += __shfl_xor(pc0[ti], off);
            pc1[ti] += __shfl_xor(pc1[ti], off);
        }
    }
    if (lane == 0){
        #pragma unroll
        for (int ti = 0; ti < TBT; ti++){
            s_xs[wave][ti]  = ps[ti];
            s_xc0[wave][ti] = pc0[ti];
            s_xc1[wave][ti] = pc1[ti];
        }
    }
    __syncthreads();

    unsigned short* wbase = wsm_b + ((size_t)n*TT + t0)*WT + w;
    #pragma unroll
    for (int ti = 0; ti < TBT; ti++){
        float S  = s_xs[0][ti] + s_xs[1][ti] + s_xs[2][ti] + s_xs[3][ti];
        float rS = fast_rcp(S);
        wbase[(size_t)ti*WT] = f2bf(e[ti] * rS);
    }
    if (tid < TBT){
        int ti = tid;
        float S  = s_xs[0][ti] + s_xs[1][ti] + s_xs[2][ti] + s_xs[3][ti];
        float rS = fast_rcp(S);
        float2 wc;
        wc.x = (s_xc0[0][ti] + s_xc0[1][ti] + s_xc0[2][ti] + s_xc0[3][ti]) * rS;
        wc.y = (s_xc1[0][ti] + s_xc1[1][ti] + s_xc1[2][ti] + s_xc1[3][ti]) * rS;
        *(float2*)(wc_g + ((size_t)n*TT + t0 + ti)*2) = wc;
    }
}

// ---------------- Kernel C1 (mid fallback): monolithic R6 score_k ----------------
__global__ __launch_bounds__(256) void score_k(
    const float* __restrict__ Tg,
    const float* __restrict__ v1g, const float* __restrict__ v2g,
    const float* __restrict__ sb1w1, const float* __restrict__ sb1w2, const float* __restrict__ sb1b2,
    const float* __restrict__ sb2w1, const float* __restrict__ sb2w2, const float* __restrict__ sb2b2,
    const float* __restrict__ p2w, const float* __restrict__ p2b,
    unsigned short* __restrict__ wsm_b, float* __restrict__ wc_g)
{
    int n   = blockIdx.y;
    int t0  = blockIdx.x * TBT;
    int tid = threadIdx.x;
    int w   = tid;
    int lane = tid & 63, wave = tid >> 6;

    __shared__ float s_w2[16*16];
    __shared__ float s_u2[16], s_b2[16], s_p2w[16];
    __shared__ float s_u1[2], s_w21[4], s_b21[2];
    __shared__ float s_xa[4][TBT];
    __shared__ float s_xs[4][TBT];
    __shared__ float s_xc0[4][TBT], s_xc1[4][TBT];

    s_w2[tid] = sb2w2[tid];
    if (tid < 16){
        s_u2[tid]  = sb2w1[tid] - sb2w1[16 + tid];
        s_b2[tid]  = sb2b2[tid];
        s_p2w[tid] = p2w[tid];
    } else if (tid < 18){
        int p = tid - 16;
        s_u1[p]  = sb1w1[p] - sb1w1[2 + p];
        s_b21[p] = sb1b2[p];
    } else if (tid < 22){
        s_w21[tid - 18] = sb1w2[tid - 18];
    }
    __syncthreads();

    float v2r[16];
    {
        const float4* vp = (const float4*)(v2g + (size_t)(n*WT + w)*16);
        float4 a = vp[0], b = vp[1], c = vp[2], d = vp[3];
        v2r[0]=a.x; v2r[1]=a.y; v2r[2]=a.z; v2r[3]=a.w;
        v2r[4]=b.x; v2r[5]=b.y; v2r[6]=b.z; v2r[7]=b.w;
        v2r[8]=c.x; v2r[9]=c.y; v2r[10]=c.z; v2r[11]=c.w;
        v2r[12]=d.x; v2r[13]=d.y; v2r[14]=d.z; v2r[15]=d.w;
    }
    float v1r0, v1r1;
    {
        const float* vp = v1g + (size_t)(n*WT + w)*2;
        v1r0 = vp[0]; v1r1 = vp[1];
    }
    float p2bv = p2b[0];
    float tv[TBT];
    #pragma unroll
    for (int ti = 0; ti < TBT; ti++) tv[ti] = Tg[t0 + ti];

    unsigned mpos = 0u, mneg = 0u;
    #pragma unroll
    for (int i = 0; i < 16; i++){
        float u = s_u2[i], v = v2r[i];
        float xa = fmaf(tv[0],     u, v);
        float xb = fmaf(tv[TBT-1], u, v);
        float lo = fminf(xa, xb), hi = fmaxf(xa, xb);
        if (__all(lo >  20.0f)) mpos |= (1u << i);
        else if (__all(hi < -20.0f)) mneg |= (1u << i);
    }
    unsigned mact = 0xFFFFu & ~(mpos | mneg);

    float scores[TBT];
    if (mact == 0u){
        float hA[16], hB[16];
        #pragma unroll
        for (int j = 0; j < 16; j++){ hA[j] = s_b2[j]; hB[j] = 0.0f; }
        #pragma unroll
        for (int i = 0; i < 16; i++){
            if (mpos & (1u << i)){
                float u = s_u2[i], v = v2r[i];
                #pragma unroll
                for (int j = 0; j < 16; j++){
                    float wv = s_w2[i*16 + j];
                    hA[j] = fmaf(v, wv, hA[j]);
                    hB[j] = fmaf(u, wv, hB[j]);
                }
            }
        }
        unsigned jpos = 0u, jact = 0u;
        #pragma unroll
        for (int j = 0; j < 16; j++){
            float h0 = fmaf(tv[0],     hB[j], hA[j]);
            float h7 = fmaf(tv[TBT-1], hB[j], hA[j]);
            float lo = fminf(h0, h7), hi = fmaxf(h0, h7);
            unsigned p  = (unsigned)__all(lo > 20.0f);
            unsigned nn = (unsigned)__all(hi < -20.0f);
            jpos |= p << j;
            jact |= ((p | nn) ^ 1u) << j;
        }
        float SA = p2bv, SB = 0.0f;
        #pragma unroll
        for (int j = 0; j < 16; j++){
            float pw = s_p2w[j] * (float)((jpos >> j) & 1u);
            SA = fmaf(hA[j], pw, SA);
            SB = fmaf(hB[j], pw, SB);
        }
        #pragma unroll
        for (int ti = 0; ti < TBT; ti++) scores[ti] = fmaf(tv[ti], SB, SA);
        #pragma unroll
        for (int j = 0; j < 16; j++){
            if (jact & (1u << j)){
                float pw = s_p2w[j];
                float a = hA[j], b = hB[j];
                #pragma unroll
                for (int ti = 0; ti < TBT; ti++)
                    scores[ti] = fmaf(silu_f(fmaf(tv[ti], b, a)), pw, scores[ti]);
            }
        }
    } else {
        #pragma unroll
        for (int tp = 0; tp < TBT; tp += 2){
            float h2a[16], h2b[16];
            #pragma unroll
            for (int j = 0; j < 16; j++){ float b = s_b2[j]; h2a[j] = b; h2b[j] = b; }
            #pragma unroll
            for (int i = 0; i < 16; i++){
                if (mneg & (1u << i)) continue;
                float u = s_u2[i], v = v2r[i];
                float aa = fmaf(tv[tp],   u, v);
                float ab = fmaf(tv[tp+1], u, v);
                if (!(mpos & (1u << i))){
                    aa = silu_f(aa);
                    ab = silu_f(ab);
                }
                #pragma unroll
                for (int j = 0; j < 16; j++){
                    float wv = s_w2[i*16 + j];
                    h2a[j] = fmaf(aa, wv, h2a[j]);
                    h2b[j] = fmaf(ab, wv, h2b[j]);
                }
            }
            float sa = p2bv, sb = p2bv;
            #pragma unroll
            for (int j = 0; j < 16; j++){
                float pw = s_p2w[j];
                float ha = h2a[j], hb = h2b[j];
                if (__all(fminf(ha, hb) > 20.0f)){
                    sa = fmaf(ha, pw, sa);
                    sb = fmaf(hb, pw, sb);
                } else if (__all(fmaxf(ha, hb) < -20.0f)){
                } else {
                    sa = fmaf(silu_f(ha), pw, sa);
                    sb = fmaf(silu_f(hb), pw, sb);
                }
            }
            scores[tp] = sa; scores[tp+1] = sb;
        }
    }

    float c0r[TBT], c1r[TBT];
    {
        float u10 = s_u1[0], u11 = s_u1[1];
        float w00 = s_w21[0], w01 = s_w21[1], w10 = s_w21[2], w11 = s_w21[3];
        float b0 = s_b21[0], b1 = s_b21[1];
        float x0a = fmaf(tv[0], u10, v1r0), x0b = fmaf(tv[TBT-1], u10, v1r0);
        float x1a = fmaf(tv[0], u11, v1r1), x1b = fmaf(tv[TBT-1], u11, v1r1);
        bool p0 = __all(fminf(x0a, x0b) >  20.0f);
        bool n0 = __all(fmaxf(x0a, x0b) < -20.0f);
        bool p1 = __all(fminf(x1a, x1b) >  20.0f);
        bool n1 = __all(fmaxf(x1a, x1b) < -20.0f);
        #pragma unroll
        for (int ti = 0; ti < TBT; ti++){
            float x0 = fmaf(tv[ti], u10, v1r0);
            float x1 = fmaf(tv[ti], u11, v1r1);
            float gl0, gl1;
            if (p0)      gl0 = x0;
            else if (n0) gl0 = 0.0f;
            else         gl0 = silu_f(x0);
            if (p1)      gl1 = x1;
            else if (n1) gl1 = 0.0f;
            else         gl1 = silu_f(x1);
            float y0 = fmaf(gl0, w00, fmaf(gl1, w10, b0));
            float y1 = fmaf(gl0, w01, fmaf(gl1, w11, b1));
            if (__all(fminf(y0, y1) > 20.0f)){
                c0r[ti] = y0; c1r[ti] = y1;
            } else if (__all(fmaxf(y0, y1) < -20.0f)){
                c0r[ti] = 0.0f; c1r[ti] = 0.0f;
            } else {
                c0r[ti] = silu_f(y0); c1r[ti] = silu_f(y1);
            }
        }
    }

    float m[TBT];
    #pragma unroll
    for (int ti = 0; ti < TBT; ti++) m[ti] = scores[ti];
    #pragma unroll
    for (int off = 32; off; off >>= 1){
        #pragma unroll
        for (int ti = 0; ti < TBT; ti++) m[ti] = fmaxf(m[ti], __shfl_xor(m[ti], off));
    }
    if (lane == 0){
        #pragma unroll
        for (int ti = 0; ti < TBT; ti++) s_xa[wave][ti] = m[ti];
    }
    __syncthreads();
    #pragma unroll
    for (int ti = 0; ti < TBT; ti++)
        m[ti] = fmaxf(fmaxf(s_xa[0][ti], s_xa[1][ti]), fmaxf(s_xa[2][ti], s_xa[3][ti]));

    float e[TBT], ps[TBT], pc0[TBT], pc1[TBT];
    #pragma unroll
    for (int ti = 0; ti < TBT; ti++){
        e[ti]   = __expf(scores[ti] - m[ti]);
        ps[ti]  = e[ti];
        pc0[ti] = e[ti] * c0r[ti];
        pc1[ti] = e[ti] * c1r[ti];
    }
    #pragma unroll
    for (int off = 32; off; off >>= 1){
        #pragma unroll
        for (int ti = 0; ti < TBT; ti++){
            ps[ti]  += __shfl_xor(ps[ti],  off);
            pc0[ti] += __shfl_xor(pc0[ti], off);
            pc1[ti] += __shfl_xor(pc1[ti], off);
        }
    }
    if (lane == 0){
        #pragma unroll
        for (int ti = 0; ti < TBT; ti++){
            s_xs[wave][ti]  = ps[ti];
            s_xc0[wave][ti] = pc0[ti];
            s_xc1[wave][ti] = pc1[ti];
        }
    }
    __syncthreads();

    unsigned short* wbase = wsm_b + ((size_t)n*TT + t0)*WT + w;
    #pragma unroll
    for (int ti = 0; ti < TBT; ti++){
        float S  = s_xs[0][ti] + s_xs[1][ti] + s_xs[2][ti] + s_xs[3][ti];
        float rS = fast_rcp(S);
        wbase[(size_t)ti*WT] = f2bf(e[ti] * rS);
    }
    if (tid < TBT){
        int ti = tid;
        float S  = s_xs[0][ti] + s_xs[1][ti] + s_xs[2][ti] + s_xs[3][ti];
        float rS = fast_rcp(S);
        float2 wc;
        wc.x = (s_xc0[0][ti] + s_xc0[1][ti] + s_xc0[2][ti] + s_xc0[3][ti]) * rS;
        wc.y = (s_xc1[0][ti] + s_xc1[1][ti] + s_xc1[2][ti] + s_xc1[3][ti]) * rS;
        *(float2*)(wc_g + ((size_t)n*TT + t0 + ti)*2) = wc;
    }
}

// ---------------- Kernel C2: out_r via bf16 MFMA GEMM + epilogue (R7 form) ----------------
__global__ __launch_bounds__(512) void outr_mfma_k(
    const unsigned short* __restrict__ wsmB, const unsigned short* __restrict__ featP,
    const float* __restrict__ wc_g,
    const float* __restrict__ p1w, const float* __restrict__ p1b,
    float* __restrict__ out)
{
    int n    = blockIdx.y;
    int t0   = blockIdx.x * 32;
    int tid  = threadIdx.x;
    int lane = tid & 63, wave = tid >> 6;
    int tw   = t0 + (wave >> 2) * 16;    // waves 0-3 -> t0, 4-7 -> t0+16
    int dbase = (wave & 3) * 4;          // 4 dt-blocks (64 d) per wave
    int l15  = lane & 15, quad = lane >> 4;

    f32x4 acc[4];
    #pragma unroll
    for (int dt = 0; dt < 4; dt++) acc[dt] = (f32x4){0.f, 0.f, 0.f, 0.f};

    const unsigned short* aPtr = wsmB + ((size_t)(n*TT + tw + l15))*WT + quad*8;

    #pragma unroll
    for (int kb = 0; kb < 8; kb++){
        short8_t af = *(const short8_t*)(aPtr + kb*32);
        const unsigned short* bp = featP + ((size_t)(n*8 + kb)*DIM + dbase*16 + l15)*32 + quad*8;
        #pragma unroll
        for (int dt = 0; dt < 4; dt++){
            short8_t bf = *(const short8_t*)(bp + (size_t)dt*16*32);
            acc[dt] = __builtin_amdgcn_mfma_f32_16x16x32_bf16(af, bf, acc[dt], 0, 0, 0);
        }
    }

    float wc0[4], wc1[4];
    #pragma unroll
    for (int r = 0; r < 4; r++){
        const float* wp = wc_g + ((size_t)(n*TT + tw + quad*4 + r))*2;
        wc0[r] = wp[0]; wc1[r] = wp[1];
    }
    float* obase = out + ((size_t)(n*TT + tw + quad*4))*DIM;
    #pragma unroll
    for (int dt = 0; dt < 4; dt++){
        int d = (dbase + dt)*16 + l15;   // D col
        float pa = p1w[d], pb2 = p1w[DIM + d], pc = p1b[d];
        #pragma unroll
        for (int r = 0; r < 4; r++){     // D row = quad*4 + r
            float val = acc[dt][r] + fmaf(wc0[r], pa, fmaf(wc1[r], pb2, pc));
            obase[(size_t)r*DIM + d] = val;
        }
    }
}

// ---------------- Fallback fused kernel (R1, known-good) if ws too small ----------------
__global__ __launch_bounds__(256) void fused_k(
    const float* __restrict__ Tg, const float* __restrict__ feat,
    const float* __restrict__ v1g, const float* __restrict__ v2g,
    const float* __restrict__ sb1w1, const float* __restrict__ sb1w2, const float* __restrict__ sb1b2,
    const float* __restrict__ sb2w1, const float* __restrict__ sb2w2, const float* __restrict__ sb2b2,
    const float* __restrict__ p1w, const float* __restrict__ p1b,
    const float* __restrict__ p2w, const float* __restrict__ p2b,
    float* __restrict__ out)
{
    int n   = blockIdx.y;
    int t0  = blockIdx.x * TBT;
    int tid = threadIdx.x;
    int w   = tid;
    int lane = tid & 63, wave = tid >> 6;

    __shared__ float s_w2[16*16];
    __shared__ float s_u2[16], s_b2[16], s_p2w[16];
    __shared__ float s_u1[2], s_w21[4], s_b21[2];
    __shared__ float s_wsmT[WT][TBT];
    __shared__ float s_xa[4][TBT];
    __shared__ float s_xs[4][TBT];
    __shared__ float s_xc0[4][TBT], s_xc1[4][TBT];
    __shared__ float s_wc0[TBT], s_wc1[TBT];
    __shared__ float s_out[4][DIM];

    s_w2[tid] = sb2w2[tid];
    if (tid < 16){
        s_u2[tid]  = sb2w1[tid] - sb2w1[16 + tid];
        s_b2[tid]  = sb2b2[tid];
        s_p2w[tid] = p2w[tid];
    } else if (tid < 18){
        int p = tid - 16;
        s_u1[p]  = sb1w1[p] - sb1w1[2 + p];
        s_b21[p] = sb1b2[p];
    } else if (tid < 22){
        s_w21[tid - 18] = sb1w2[tid - 18];
    }
    __syncthreads();

    float v2r[16];
    {
        const float4* vp = (const float4*)(v2g + (size_t)(n*WT + w)*16);
        float4 a = vp[0], b = vp[1], c = vp[2], d = vp[3];
        v2r[0]=a.x; v2r[1]=a.y; v2r[2]=a.z; v2r[3]=a.w;
        v2r[4]=b.x; v2r[5]=b.y; v2r[6]=b.z; v2r[7]=b.w;
        v2r[8]=c.x; v2r[9]=c.y; v2r[10]=c.z; v2r[11]=c.w;
        v2r[12]=d.x; v2r[13]=d.y; v2r[14]=d.z; v2r[15]=d.w;
    }
    float v1r0, v1r1;
    {
        const float* vp = v1g + (size_t)(n*WT + w)*2;
        v1r0 = vp[0]; v1r1 = vp[1];
    }
    float p2bv = p2b[0];
    float tv[TBT];
    #pragma unroll
    for (int ti = 0; ti < TBT; ti++) tv[ti] = Tg[t0 + ti];

    float scores[TBT];
    #pragma unroll
    for (int tp = 0; tp < TBT; tp += 2){
        float h2a[16], h2b[16];
        #pragma unroll
        for (int j = 0; j < 16; j++){ float b = s_b2[j]; h2a[j] = b; h2b[j] = b; }
        #pragma unroll
        for (int i = 0; i < 16; i++){
            float u = s_u2[i], v = v2r[i];
            float aa = silu_f(fmaf(tv[tp],   u, v));
            float ab = silu_f(fmaf(tv[tp+1], u, v));
            #pragma unroll
            for (int j = 0; j < 16; j++){
                float wv = s_w2[i*16 + j];
                h2a[j] = fmaf(aa, wv, h2a[j]);
                h2b[j] = fmaf(ab, wv, h2b[j]);
            }
        }
        float sa = p2bv, sb = p2bv;
        #pragma unroll
        for (int j = 0; j < 16; j++){
            float pw = s_p2w[j];
            sa = fmaf(silu_f(h2a[j]), pw, sa);
            sb = fmaf(silu_f(h2b[j]), pw, sb);
        }
        scores[tp] = sa; scores[tp+1] = sb;
    }

    float c0r[TBT], c1r[TBT];
    {
        float u10 = s_u1[0], u11 = s_u1[1];
        float w00 = s_w21[0], w01 = s_w21[1], w10 = s_w21[2], w11 = s_w21[3];
        float b0 = s_b21[0], b1 = s_b21[1];
        #pragma unroll
        for (int ti = 0; ti < TBT; ti++){
            float gl0 = silu_f(fmaf(tv[ti], u10, v1r0));
            float gl1 = silu_f(fmaf(tv[ti], u11, v1r1));
            c0r[ti] = silu_f(fmaf(gl0, w00, fmaf(gl1, w10, b0)));
            c1r[ti] = silu_f(fmaf(gl0, w01, fmaf(gl1, w11, b1)));
        }
    }

    float m[TBT];
    #pragma unroll
    for (int ti = 0; ti < TBT; ti++) m[ti] = scores[ti];
    #pragma unroll
    for (int off = 32; off; off >>= 1){
        #pragma unroll
        for (int ti = 0; ti < TBT; ti++) m[ti] = fmaxf(m[ti], __shfl_xor(m[ti], off));
    }
    if (lane == 0){
        #pragma unroll
        for (int ti = 0; ti < TBT; ti++) s_xa[wave][ti] = m[ti];
    }
    __syncthreads();
    #pragma unroll
    for (int ti = 0; ti < TBT; ti++)
        m[ti] = fmaxf(fmaxf(s_xa[0][ti], s_xa[1][ti]), fmaxf(s_xa[2][ti], s_xa[3][ti]));

    float e[TBT], ps[TBT], pc0[TBT], pc1[TBT];
    #pragma unroll
    for (int ti = 0; ti < TBT; ti++){
        e[ti]  = __expf(scores[ti] - m[ti]);
        ps[ti] = e[ti];
        pc0[ti] = e[ti] * c0r[ti];
        pc1[ti] = e[ti] * c1r[ti];
    }
    #pragma unroll
    for (int off = 32; off; off >>= 1){
        #pragma unroll
        for (int ti = 0; ti < TBT; ti++){
            ps[ti]  += __shfl_xor(ps[ti],  off);
            pc0[ti] += __shfl_xor(pc0[ti], off);
            pc1[ti] += __shfl_xor(pc1[ti], off);
        }
    }
    if (lane == 0){
        #pragma unroll
        for (int ti = 0; ti < TBT; ti++){
            s_xs[wave][ti]  = ps[ti];
            s_xc0[wave][ti] = pc0[ti];
            s_xc1[wave][ti] = pc1[ti];
        }
    }
    __syncthreads();
    #pragma unroll
    for (int ti = 0; ti < TBT; ti++){
        float S  = s_xs[0][ti] + s_xs[1][ti] + s_xs[2][ti] + s_xs[3][ti];
        float rS = fast_rcp(S);
        s_wsmT[w][ti] = e[ti] * rS;
    }
    if (tid < TBT){
        int ti = tid;
        float S  = s_xs[0][ti] + s_xs[1][ti] + s_xs[2][ti] + s_xs[3][ti];
        float rS = fast_rcp(S);
        s_wc0[ti] = (s_xc0[0][ti] + s_xc0[1][ti] + s_xc0[2][ti] + s_xc0[3][ti]) * rS;
        s_wc1[ti] = (s_xc1[0][ti] + s_xc1[1][ti] + s_xc1[2][ti] + s_xc1[3][ti]) * rS;
    }
    __syncthreads();

    int wid = wave;
    int dq  = lane;
    const float* fbase = feat + (size_t)n*WT*DIM + dq*4;
    float4 acc[TBT];
    #pragma unroll
    for (int i = 0; i < TBT; i++) acc[i] = make_float4(0.f, 0.f, 0.f, 0.f);

    #pragma unroll 4
    for (int w0 = wid; w0 < WT; w0 += 4){
        float4 f = *(const float4*)(fbase + (size_t)w0*DIM);
        const float4* wp = (const float4*)&s_wsmT[w0][0];
        float4 wA = wp[0], wB = wp[1];
        fma4(acc[0], wA.x, f); fma4(acc[1], wA.y, f);
        fma4(acc[2], wA.z, f); fma4(acc[3], wA.w, f);
        fma4(acc[4], wB.x, f); fma4(acc[5], wB.y, f);
        fma4(acc[6], wB.z, f); fma4(acc[7], wB.w, f);
    }

    float pw0 = p1w[tid], pw1 = p1w[DIM + tid], pbv = p1b[tid];
    float* orow = out + ((size_t)n*TT + t0)*DIM;
    #pragma unroll
    for (int ti = 0; ti < TBT; ti++){
        __syncthreads();
        *(float4*)&s_out[wid][dq*4] = acc[ti];
        __syncthreads();
        float r = s_out[0][tid] + s_out[1][tid] + s_out[2][tid] + s_out[3][tid];
        float o = fmaf(s_wc0[ti], pw0, fmaf(s_wc1[ti], pw1, r + pbv));
        orow[(size_t)ti*DIM + tid] = o;
    }
}

extern "C" void kernel_launch(void* const* d_in, const int* in_sizes, int n_in,
                              void* d_out, int out_size, void* d_ws, size_t ws_size,
                              hipStream_t stream)
{
    const float* Tg    = (const float*)d_in[0];
    const float* dur   = (const float*)d_in[1];
    const float* feat  = (const float*)d_in[2];
    const float* c1w   = (const float*)d_in[3];
    const float* c1b   = (const float*)d_in[4];
    const float* bn1g  = (const float*)d_in[5];
    const float* bn1b  = (const float*)d_in[6];
    const float* bn1m  = (const float*)d_in[7];
    const float* bn1v  = (const float*)d_in[8];
    const float* c2w   = (const float*)d_in[9];
    const float* c2b   = (const float*)d_in[10];
    const float* bn2g  = (const float*)d_in[11];
    const float* bn2b  = (const float*)d_in[12];
    const float* bn2m  = (const float*)d_in[13];
    const float* bn2v  = (const float*)d_in[14];
    const float* sb1w1 = (const float*)d_in[15];
    const float* sb1b1 = (const float*)d_in[16];
    const float* sb1w2 = (const float*)d_in[17];
    const float* sb1b2 = (const float*)d_in[18];
    const float* sb2w1 = (const float*)d_in[19];
    const float* sb2b1 = (const float*)d_in[20];
    const float* sb2w2 = (const float*)d_in[21];
    const float* sb2b2 = (const float*)d_in[22];
    const float* p1w   = (const float*)d_in[23];
    const float* p1b   = (const float*)d_in[24];
    const float* p2w   = (const float*)d_in[25];
    const float* p2b   = (const float*)d_in[26];
    float* out = (float*)d_out;

    // ws layout (float units): v1[8192] v2[65536] wc[65536]
    // then bf16: wsmB[NN*TT*WT] featP[NN*WT*DIM]
    // then (split path): scr[NN*TT*WT] f32, hA[NN*WT*16] f32, hB[16] f32, T1N[NN] f32
    float* ws = (float*)d_ws;
    float* v1  = ws;
    float* v2  = ws + 8192;
    float* wc  = ws + 8192 + 65536;
    unsigned short* wsmB  = (unsigned short*)(ws + 8192 + 65536 + 65536);
    unsigned short* featP = wsmB + (size_t)NN*TT*WT;
    float* scr = (float*)(featP + (size_t)NN*WT*DIM);
    float* hAg = scr + (size_t)NN*TT*WT;
    float* hBg = hAg + (size_t)NN*WT*16;
    float* T1N = hBg + 16;
    size_t need_old = ((size_t)8192 + 65536 + 65536)*sizeof(float)
                    + ((size_t)NN*TT*WT + (size_t)NN*WT*DIM)*sizeof(unsigned short);
    size_t need_split = need_old
                      + ((size_t)NN*TT*WT + (size_t)NN*WT*16 + 16 + NN)*sizeof(float);

    bool split = (ws_size >= need_split);

    if (split) init_k<<<1, 64, 0, stream>>>(T1N);
    prep_k<<<dim3(WT, NN), 256, 0, stream>>>(dur, feat, c1w, c1b, bn1g, bn1b, bn1m, bn1v,
                                             c2w, c2b, bn2g, bn2b, bn2m, bn2v,
                                             sb1w1, sb1b1, sb2w1, sb2b1,
                                             sb2w2, sb2b2,
                                             v1, v2,
                                             split ? hAg : nullptr,
                                             split ? hBg : nullptr,
                                             split ? T1N : nullptr);
    if (split){
        featpack_k<<<dim3(8, NN), 256, 0, stream>>>(feat, featP);
        score1_k<<<dim3(TT/TBT, NN), 256, 0, stream>>>(Tg, v2,
                                                       sb2w1, sb2w2, sb2b2,
                                                       p2w, p2b, T1N, scr);
        score2_k<<<dim3(TT/TBT, NN), 256, 0, stream>>>(Tg, v1, scr, hAg, hBg, T1N,
                                                       sb1w1, sb1w2, sb1b2,
                                                       p2w, p2b, wsmB, wc);
        outr_mfma_k<<<dim3(TT/32, NN), 512, 0, stream>>>(wsmB, featP, wc, p1w, p1b, out);
    } else if (ws_size >= need_old){
        featpack_k<<<dim3(8, NN), 256, 0, stream>>>(feat, featP);
        score_k<<<dim3(TT/TBT, NN), 256, 0, stream>>>(Tg, v1, v2,
                                                      sb1w1, sb1w2, sb1b2,
                                                      sb2w1, sb2w2, sb2b2,
                                                      p2w, p2b, wsmB, wc);
        outr_mfma_k<<<dim3(TT/32, NN), 512, 0, stream>>>(wsmB, featP, wc, p1w, p1b, out);
    } else {
        fused_k<<<dim3(TT/TBT, NN), 256, 0, stream>>>(Tg, feat, v1, v2,
                                                      sb1w1, sb1w2, sb1b2,
                                                      sb2w1, sb2w2, sb2b2,
                                                      p1w, p1b, p2w, p2b, out);
    }
}

// Round 9
// 277.617 us; speedup vs baseline: 1.1263x; 1.1263x over previous
//
#include <hip/hip_runtime.h>
#include <hip/hip_bf16.h>

#define NN  16
#define WT  256
#define TT  2048
#define DIM 256
#define TBT 8      // t-values per block in score kernel

typedef __attribute__((ext_vector_type(8))) short short8_t;  // 8 bf16 (4 VGPRs)
typedef __attribute__((ext_vector_type(4))) float f32x4;     // MFMA acc

__device__ __forceinline__ float fast_rcp(float x){ return __builtin_amdgcn_rcpf(x); }

__device__ __forceinline__ float silu_f(float x){
    return x * fast_rcp(1.0f + __expf(-x));
}

__device__ __forceinline__ unsigned short f2bf(float x){
    union { float f; unsigned u; } v; v.f = x;
    unsigned r = v.u + 0x7FFFu + ((v.u >> 16) & 1u);   // round-to-nearest-even
    return (unsigned short)(r >> 16);
}

__device__ __forceinline__ void fma4(float4& a, float s, const float4& f){
    a.x = fmaf(s, f.x, a.x); a.y = fmaf(s, f.y, a.y);
    a.z = fmaf(s, f.z, a.z); a.w = fmaf(s, f.w, a.w);
}

// ------- Kernel B: cumsum (in-block scan) + conv(3,256->8)+BN+SiLU, fold into v1/v2 -------
__global__ __launch_bounds__(256) void prep_k(
    const float* __restrict__ dur, const float* __restrict__ feat,
    const float* __restrict__ c1w, const float* __restrict__ c1b,
    const float* __restrict__ g1,  const float* __restrict__ be1,
    const float* __restrict__ m1,  const float* __restrict__ vv1,
    const float* __restrict__ c2w, const float* __restrict__ c2b,
    const float* __restrict__ g2,  const float* __restrict__ be2,
    const float* __restrict__ m2,  const float* __restrict__ vv2,
    const float* __restrict__ sb1w1, const float* __restrict__ sb1b1,
    const float* __restrict__ sb2w1, const float* __restrict__ sb2b1,
    float* __restrict__ v1o, float* __restrict__ v2o)
{
    int w = blockIdx.x, n = blockIdx.y;
    int tid = threadIdx.x;              // channel c

    // ---- in-block inclusive scan of durations for this n ----
    __shared__ float sdur[WT];
    sdur[tid] = dur[n*WT + tid];
    __syncthreads();
    for (int off = 1; off < WT; off <<= 1){
        float v = (tid >= off) ? sdur[tid-off] : 0.0f;
        __syncthreads();
        sdur[tid] += v;
        __syncthreads();
    }
    float end   = sdur[w];              // broadcast read
    float start = end - dur[n*WT + w];  // uniform scalar load

    const float* fb = feat + (size_t)(n*WT)*DIM;
    float fm = (w > 0)    ? fb[(size_t)(w-1)*DIM + tid] : 0.0f;
    float f0 =              fb[(size_t) w   *DIM + tid];
    float fp = (w < WT-1) ? fb[(size_t)(w+1)*DIM + tid] : 0.0f;

    float pl[8], pr[8];
    #pragma unroll
    for (int o = 0; o < 8; o++){
        const float* wp = c1w + (size_t)(o*DIM + tid)*3;
        pl[o] = fmaf(fm, wp[0], fmaf(f0, wp[1], fp*wp[2]));
        const float* wq = c2w + (size_t)(o*DIM + tid)*3;
        pr[o] = fmaf(fm, wq[0], fmaf(f0, wq[1], fp*wq[2]));
    }
    #pragma unroll
    for (int o = 0; o < 8; o++){
        #pragma unroll
        for (int off = 32; off; off >>= 1){
            pl[o] += __shfl_xor(pl[o], off);
            pr[o] += __shfl_xor(pr[o], off);
        }
    }
    __shared__ float sws[4][16];
    int wave = tid >> 6, lane = tid & 63;
    if (lane == 0){
        #pragma unroll
        for (int o = 0; o < 8; o++){ sws[wave][o] = pl[o]; sws[wave][8+o] = pr[o]; }
    }
    __syncthreads();
    __shared__ float slr[16];   // [0..7]=left(SiLU'd), [8..15]=right
    if (tid < 16){
        float s = sws[0][tid] + sws[1][tid] + sws[2][tid] + sws[3][tid];
        int o = tid & 7; bool isr = tid >= 8;
        float bias = isr ? c2b[o] : c1b[o];
        float mm   = isr ? m2[o]  : m1[o];
        float vv   = isr ? vv2[o] : vv1[o];
        float gg   = isr ? g2[o]  : g1[o];
        float bb   = isr ? be2[o] : be1[o];
        float y = s + bias;
        y = (y - mm) * rsqrtf(vv + 1e-5f);
        y = y * gg + bb;
        slr[tid] = silu_f(y);
    }
    __syncthreads();
    if (tid < 16){
        int j = tid;
        float acc = sb2b1[j] - start*sb2w1[j] + end*sb2w1[16 + j];
        #pragma unroll
        for (int o = 0; o < 8; o++) acc = fmaf(slr[8+o], sb2w1[(2+o)*16 + j], acc);
        v2o[(size_t)(n*WT + w)*16 + j] = acc;
    } else if (tid < 18){
        int p = tid - 16;
        float acc = sb1b1[p] - start*sb1w1[p] + end*sb1w1[2 + p];
        #pragma unroll
        for (int o = 0; o < 8; o++) acc = fmaf(slr[o], sb1w1[(2+o)*2 + p], acc);
        v1o[(size_t)(n*WT + w)*2 + p] = acc;
    }
}

// ------- Kernel B2: pack feat into B-fragment bf16 layout [n][w/32][d][w%32] -------
__global__ __launch_bounds__(256) void featpack_k(const float* __restrict__ feat,
                                                  unsigned short* __restrict__ featP)
{
    int kb = blockIdx.x, n = blockIdx.y;   // kb = 0..7 (k-block of 32 w's)
    int d = threadIdx.x;
    const float* fb = feat + (size_t)n*WT*DIM + (size_t)kb*32*DIM + d;
    unsigned short* op = featP + ((size_t)(n*8 + kb)*DIM + d)*32;
    unsigned short buf[32];
    #pragma unroll
    for (int e = 0; e < 32; e++) buf[e] = f2bf(fb[(size_t)e*DIM]);   // coalesced reads
    #pragma unroll
    for (int g = 0; g < 4; g++){
        uint4 u;
        u.x = (unsigned)buf[g*8+0] | ((unsigned)buf[g*8+1] << 16);
        u.y = (unsigned)buf[g*8+2] | ((unsigned)buf[g*8+3] << 16);
        u.z = (unsigned)buf[g*8+4] | ((unsigned)buf[g*8+5] << 16);
        u.w = (unsigned)buf[g*8+6] | ((unsigned)buf[g*8+7] << 16);
        *(uint4*)(op + g*8) = u;
    }
}

// ---------------- Kernel C1: scores -> softmax weights (bf16, to global ws) ----------------
// SESSION BEST (275.45 us total, score_k 123.3 @ VGPR 60): R5 structure + linear-
// folding tiers.  Pos-saturated i contributes W2_ij*(u_i*t + v_i) -- linear in t;
// folded ONCE per block into hA[j]/hB[j].  When no i is in transition (mact==0),
// h_j is exactly linear in t: classify j from the 2 window endpoints, fold pos-j
// into scalars SA,SB -> score = SA + SB*t.  Blocks with active i's use the tested
// per-pair path.  Exactness: silu(x)=x (<1ulp) for x>20, =0 for x<-20.
// DO NOT restructure: 8 rounds of experiments (branchless masks, persistent
// blocks, block-uniform masks, j-hoisted folds, S1/S2 split, T1N precompute)
// all landed neutral-to-catastrophic; VGPR cliffs at 64/128 killed two attempts.
__global__ __launch_bounds__(256) void score_k(
    const float* __restrict__ Tg,
    const float* __restrict__ v1g, const float* __restrict__ v2g,
    const float* __restrict__ sb1w1, const float* __restrict__ sb1w2, const float* __restrict__ sb1b2,
    const float* __restrict__ sb2w1, const float* __restrict__ sb2w2, const float* __restrict__ sb2b2,
    const float* __restrict__ p2w, const float* __restrict__ p2b,
    unsigned short* __restrict__ wsm_b, float* __restrict__ wc_g)
{
    int n   = blockIdx.y;
    int t0  = blockIdx.x * TBT;
    int tid = threadIdx.x;
    int w   = tid;
    int lane = tid & 63, wave = tid >> 6;

    __shared__ float s_w2[16*16];
    __shared__ float s_u2[16], s_b2[16], s_p2w[16];
    __shared__ float s_u1[2], s_w21[4], s_b21[2];
    __shared__ float s_xa[4][TBT];
    __shared__ float s_xs[4][TBT];
    __shared__ float s_xc0[4][TBT], s_xc1[4][TBT];

    s_w2[tid] = sb2w2[tid];
    if (tid < 16){
        s_u2[tid]  = sb2w1[tid] - sb2w1[16 + tid];
        s_b2[tid]  = sb2b2[tid];
        s_p2w[tid] = p2w[tid];
    } else if (tid < 18){
        int p = tid - 16;
        s_u1[p]  = sb1w1[p] - sb1w1[2 + p];
        s_b21[p] = sb1b2[p];
    } else if (tid < 22){
        s_w21[tid - 18] = sb1w2[tid - 18];
    }
    __syncthreads();

    float v2r[16];
    {
        const float4* vp = (const float4*)(v2g + (size_t)(n*WT + w)*16);
        float4 a = vp[0], b = vp[1], c = vp[2], d = vp[3];
        v2r[0]=a.x; v2r[1]=a.y; v2r[2]=a.z; v2r[3]=a.w;
        v2r[4]=b.x; v2r[5]=b.y; v2r[6]=b.z; v2r[7]=b.w;
        v2r[8]=c.x; v2r[9]=c.y; v2r[10]=c.z; v2r[11]=c.w;
        v2r[12]=d.x; v2r[13]=d.y; v2r[14]=d.z; v2r[15]=d.w;
    }
    float v1r0, v1r1;
    {
        const float* vp = v1g + (size_t)(n*WT + w)*2;
        v1r0 = vp[0]; v1r1 = vp[1];
    }
    float p2bv = p2b[0];
    float tv[TBT];
    #pragma unroll
    for (int ti = 0; ti < TBT; ti++) tv[ti] = Tg[t0 + ti];

    // ---- classify saturation of each a_i over this block's t-window ----
    unsigned mpos = 0u, mneg = 0u;
    #pragma unroll
    for (int i = 0; i < 16; i++){
        float u = s_u2[i], v = v2r[i];
        float xa = fmaf(tv[0],     u, v);
        float xb = fmaf(tv[TBT-1], u, v);
        float lo = fminf(xa, xb), hi = fmaxf(xa, xb);
        if (__all(lo >  20.0f)) mpos |= (1u << i);
        else if (__all(hi < -20.0f)) mneg |= (1u << i);
    }
    unsigned mact = 0xFFFFu & ~(mpos | mneg);

    float scores[TBT];
    if (mact == 0u){
        // -------- fast tier: all i saturated -> h_j exactly linear in t --------
        float hA[16], hB[16];
        #pragma unroll
        for (int j = 0; j < 16; j++){ hA[j] = s_b2[j]; hB[j] = 0.0f; }
        #pragma unroll
        for (int i = 0; i < 16; i++){
            if (mpos & (1u << i)){          // wave-uniform scalar branch
                float u = s_u2[i], v = v2r[i];
                #pragma unroll
                for (int j = 0; j < 16; j++){
                    float wv = s_w2[i*16 + j];
                    hA[j] = fmaf(v, wv, hA[j]);
                    hB[j] = fmaf(u, wv, hB[j]);
                }
            }
        }
        // classify j's from endpoints (exact: h_j linear in t), fold pos-j's
        unsigned jact = 0u;
        float SA = p2bv, SB = 0.0f;
        #pragma unroll
        for (int j = 0; j < 16; j++){
            float h0 = fmaf(tv[0],     hB[j], hA[j]);
            float h7 = fmaf(tv[TBT-1], hB[j], hA[j]);
            float lo = fminf(h0, h7), hi = fmaxf(h0, h7);
            float pw = s_p2w[j];
            if (__all(lo > 20.0f)){
                SA = fmaf(hA[j], pw, SA);
                SB = fmaf(hB[j], pw, SB);
            } else if (!__all(hi < -20.0f)){
                jact |= (1u << j);
            }
        }
        if (jact == 0u){
            #pragma unroll
            for (int ti = 0; ti < TBT; ti++) scores[ti] = fmaf(tv[ti], SB, SA);
        } else {
            #pragma unroll
            for (int ti = 0; ti < TBT; ti++){
                float s = fmaf(tv[ti], SB, SA);
                #pragma unroll
                for (int j = 0; j < 16; j++){
                    if (jact & (1u << j))
                        s = fmaf(silu_f(fmaf(tv[ti], hB[j], hA[j])), s_p2w[j], s);
                }
                scores[ti] = s;
            }
        }
    } else {
        // -------- slow tier: round-1 per-pair path (tested) --------
        #pragma unroll
        for (int tp = 0; tp < TBT; tp += 2){
            float h2a[16], h2b[16];
            #pragma unroll
            for (int j = 0; j < 16; j++){ float b = s_b2[j]; h2a[j] = b; h2b[j] = b; }
            #pragma unroll
            for (int i = 0; i < 16; i++){
                if (mneg & (1u << i)) continue;           // a == 0: skip fan-out
                float u = s_u2[i], v = v2r[i];
                float aa = fmaf(tv[tp],   u, v);
                float ab = fmaf(tv[tp+1], u, v);
                if (!(mpos & (1u << i))){                 // not linear-saturated
                    aa = silu_f(aa);
                    ab = silu_f(ab);
                }
                #pragma unroll
                for (int j = 0; j < 16; j++){
                    float wv = s_w2[i*16 + j];
                    h2a[j] = fmaf(aa, wv, h2a[j]);
                    h2b[j] = fmaf(ab, wv, h2b[j]);
                }
            }
            float sa = p2bv, sb = p2bv;
            #pragma unroll
            for (int j = 0; j < 16; j++){
                float pw = s_p2w[j];
                float ha = h2a[j], hb = h2b[j];
                if (__all(fminf(ha, hb) > 20.0f)){
                    sa = fmaf(ha, pw, sa);
                    sb = fmaf(hb, pw, sb);
                } else if (__all(fmaxf(ha, hb) < -20.0f)){
                    // silu(h) ~ 0: no contribution
                } else {
                    sa = fmaf(silu_f(ha), pw, sa);
                    sb = fmaf(silu_f(hb), pw, sb);
                }
            }
            scores[tp] = sa; scores[tp+1] = sb;
        }
    }

    float c0r[TBT], c1r[TBT];
    {
        float u10 = s_u1[0], u11 = s_u1[1];
        float w00 = s_w21[0], w01 = s_w21[1], w10 = s_w21[2], w11 = s_w21[3];
        float b0 = s_b21[0], b1 = s_b21[1];
        // classify gl0/gl1 over the block window (same monotone-endpoint trick)
        float x0a = fmaf(tv[0], u10, v1r0), x0b = fmaf(tv[TBT-1], u10, v1r0);
        float x1a = fmaf(tv[0], u11, v1r1), x1b = fmaf(tv[TBT-1], u11, v1r1);
        bool p0 = __all(fminf(x0a, x0b) >  20.0f);
        bool n0 = __all(fmaxf(x0a, x0b) < -20.0f);
        bool p1 = __all(fminf(x1a, x1b) >  20.0f);
        bool n1 = __all(fmaxf(x1a, x1b) < -20.0f);
        #pragma unroll
        for (int ti = 0; ti < TBT; ti++){
            float x0 = fmaf(tv[ti], u10, v1r0);
            float x1 = fmaf(tv[ti], u11, v1r1);
            float gl0, gl1;
            if (p0)      gl0 = x0;
            else if (n0) gl0 = 0.0f;
            else         gl0 = silu_f(x0);
            if (p1)      gl1 = x1;
            else if (n1) gl1 = 0.0f;
            else         gl1 = silu_f(x1);
            float y0 = fmaf(gl0, w00, fmaf(gl1, w10, b0));
            float y1 = fmaf(gl0, w01, fmaf(gl1, w11, b1));
            if (__all(fminf(y0, y1) > 20.0f)){
                c0r[ti] = y0; c1r[ti] = y1;
            } else if (__all(fmaxf(y0, y1) < -20.0f)){
                c0r[ti] = 0.0f; c1r[ti] = 0.0f;
            } else {
                c0r[ti] = silu_f(y0); c1r[ti] = silu_f(y1);
            }
        }
    }

    float m[TBT];
    #pragma unroll
    for (int ti = 0; ti < TBT; ti++) m[ti] = scores[ti];
    #pragma unroll
    for (int off = 32; off; off >>= 1){
        #pragma unroll
        for (int ti = 0; ti < TBT; ti++) m[ti] = fmaxf(m[ti], __shfl_xor(m[ti], off));
    }
    if (lane == 0){
        #pragma unroll
        for (int ti = 0; ti < TBT; ti++) s_xa[wave][ti] = m[ti];
    }
    __syncthreads();
    #pragma unroll
    for (int ti = 0; ti < TBT; ti++)
        m[ti] = fmaxf(fmaxf(s_xa[0][ti], s_xa[1][ti]), fmaxf(s_xa[2][ti], s_xa[3][ti]));

    float e[TBT], ps[TBT], pc0[TBT], pc1[TBT];
    #pragma unroll
    for (int ti = 0; ti < TBT; ti++){
        e[ti]   = __expf(scores[ti] - m[ti]);
        ps[ti]  = e[ti];
        pc0[ti] = e[ti] * c0r[ti];
        pc1[ti] = e[ti] * c1r[ti];
    }
    #pragma unroll
    for (int off = 32; off; off >>= 1){
        #pragma unroll
        for (int ti = 0; ti < TBT; ti++){
            ps[ti]  += __shfl_xor(ps[ti],  off);
            pc0[ti] += __shfl_xor(pc0[ti], off);
            pc1[ti] += __shfl_xor(pc1[ti], off);
        }
    }
    if (lane == 0){
        #pragma unroll
        for (int ti = 0; ti < TBT; ti++){
            s_xs[wave][ti]  = ps[ti];
            s_xc0[wave][ti] = pc0[ti];
            s_xc1[wave][ti] = pc1[ti];
        }
    }
    __syncthreads();

    unsigned short* wbase = wsm_b + ((size_t)n*TT + t0)*WT + w;
    #pragma unroll
    for (int ti = 0; ti < TBT; ti++){
        float S  = s_xs[0][ti] + s_xs[1][ti] + s_xs[2][ti] + s_xs[3][ti];
        float rS = fast_rcp(S);
        wbase[(size_t)ti*WT] = f2bf(e[ti] * rS);
    }
    if (tid < TBT){
        int ti = tid;
        float S  = s_xs[0][ti] + s_xs[1][ti] + s_xs[2][ti] + s_xs[3][ti];
        float rS = fast_rcp(S);
        float2 wc;
        wc.x = (s_xc0[0][ti] + s_xc0[1][ti] + s_xc0[2][ti] + s_xc0[3][ti]) * rS;
        wc.y = (s_xc1[0][ti] + s_xc1[1][ti] + s_xc1[2][ti] + s_xc1[3][ti]) * rS;
        *(float2*)(wc_g + ((size_t)n*TT + t0 + ti)*2) = wc;
    }
}

// ---------------- Kernel C2: out_r via bf16 MFMA GEMM + epilogue (R7 form) ----------------
__global__ __launch_bounds__(512) void outr_mfma_k(
    const unsigned short* __restrict__ wsmB, const unsigned short* __restrict__ featP,
    const float* __restrict__ wc_g,
    const float* __restrict__ p1w, const float* __restrict__ p1b,
    float* __restrict__ out)
{
    int n    = blockIdx.y;
    int t0   = blockIdx.x * 32;
    int tid  = threadIdx.x;
    int lane = tid & 63, wave = tid >> 6;
    int tw   = t0 + (wave >> 2) * 16;    // waves 0-3 -> t0, 4-7 -> t0+16
    int dbase = (wave & 3) * 4;          // 4 dt-blocks (64 d) per wave
    int l15  = lane & 15, quad = lane >> 4;

    f32x4 acc[4];
    #pragma unroll
    for (int dt = 0; dt < 4; dt++) acc[dt] = (f32x4){0.f, 0.f, 0.f, 0.f};

    const unsigned short* aPtr = wsmB + ((size_t)(n*TT + tw + l15))*WT + quad*8;

    #pragma unroll
    for (int kb = 0; kb < 8; kb++){
        short8_t af = *(const short8_t*)(aPtr + kb*32);
        const unsigned short* bp = featP + ((size_t)(n*8 + kb)*DIM + dbase*16 + l15)*32 + quad*8;
        #pragma unroll
        for (int dt = 0; dt < 4; dt++){
            short8_t bf = *(const short8_t*)(bp + (size_t)dt*16*32);
            acc[dt] = __builtin_amdgcn_mfma_f32_16x16x32_bf16(af, bf, acc[dt], 0, 0, 0);
        }
    }

    float wc0[4], wc1[4];
    #pragma unroll
    for (int r = 0; r < 4; r++){
        const float* wp = wc_g + ((size_t)(n*TT + tw + quad*4 + r))*2;
        wc0[r] = wp[0]; wc1[r] = wp[1];
    }
    float* obase = out + ((size_t)(n*TT + tw + quad*4))*DIM;
    #pragma unroll
    for (int dt = 0; dt < 4; dt++){
        int d = (dbase + dt)*16 + l15;   // D col
        float pa = p1w[d], pb2 = p1w[DIM + d], pc = p1b[d];
        #pragma unroll
        for (int r = 0; r < 4; r++){     // D row = quad*4 + r
            float val = acc[dt][r] + fmaf(wc0[r], pa, fmaf(wc1[r], pb2, pc));
            obase[(size_t)r*DIM + d] = val;
        }
    }
}

// ---------------- Fallback fused kernel (R1, known-good) if ws too small ----------------
__global__ __launch_bounds__(256) void fused_k(
    const float* __restrict__ Tg, const float* __restrict__ feat,
    const float* __restrict__ v1g, const float* __restrict__ v2g,
    const float* __restrict__ sb1w1, const float* __restrict__ sb1w2, const float* __restrict__ sb1b2,
    const float* __restrict__ sb2w1, const float* __restrict__ sb2w2, const float* __restrict__ sb2b2,
    const float* __restrict__ p1w, const float* __restrict__ p1b,
    const float* __restrict__ p2w, const float* __restrict__ p2b,
    float* __restrict__ out)
{
    int n   = blockIdx.y;
    int t0  = blockIdx.x * TBT;
    int tid = threadIdx.x;
    int w   = tid;
    int lane = tid & 63, wave = tid >> 6;

    __shared__ float s_w2[16*16];
    __shared__ float s_u2[16], s_b2[16], s_p2w[16];
    __shared__ float s_u1[2], s_w21[4], s_b21[2];
    __shared__ float s_wsmT[WT][TBT];
    __shared__ float s_xa[4][TBT];
    __shared__ float s_xs[4][TBT];
    __shared__ float s_xc0[4][TBT], s_xc1[4][TBT];
    __shared__ float s_wc0[TBT], s_wc1[TBT];
    __shared__ float s_out[4][DIM];

    s_w2[tid] = sb2w2[tid];
    if (tid < 16){
        s_u2[tid]  = sb2w1[tid] - sb2w1[16 + tid];
        s_b2[tid]  = sb2b2[tid];
        s_p2w[tid] = p2w[tid];
    } else if (tid < 18){
        int p = tid - 16;
        s_u1[p]  = sb1w1[p] - sb1w1[2 + p];
        s_b21[p] = sb1b2[p];
    } else if (tid < 22){
        s_w21[tid - 18] = sb1w2[tid - 18];
    }
    __syncthreads();

    float v2r[16];
    {
        const float4* vp = (const float4*)(v2g + (size_t)(n*WT + w)*16);
        float4 a = vp[0], b = vp[1], c = vp[2], d = vp[3];
        v2r[0]=a.x; v2r[1]=a.y; v2r[2]=a.z; v2r[3]=a.w;
        v2r[4]=b.x; v2r[5]=b.y; v2r[6]=b.z; v2r[7]=b.w;
        v2r[8]=c.x; v2r[9]=c.y; v2r[10]=c.z; v2r[11]=c.w;
        v2r[12]=d.x; v2r[13]=d.y; v2r[14]=d.z; v2r[15]=d.w;
    }
    float v1r0, v1r1;
    {
        const float* vp = v1g + (size_t)(n*WT + w)*2;
        v1r0 = vp[0]; v1r1 = vp[1];
    }
    float p2bv = p2b[0];
    float tv[TBT];
    #pragma unroll
    for (int ti = 0; ti < TBT; ti++) tv[ti] = Tg[t0 + ti];

    float scores[TBT];
    #pragma unroll
    for (int tp = 0; tp < TBT; tp += 2){
        float h2a[16], h2b[16];
        #pragma unroll
        for (int j = 0; j < 16; j++){ float b = s_b2[j]; h2a[j] = b; h2b[j] = b; }
        #pragma unroll
        for (int i = 0; i < 16; i++){
            float u = s_u2[i], v = v2r[i];
            float aa = silu_f(fmaf(tv[tp],   u, v));
            float ab = silu_f(fmaf(tv[tp+1], u, v));
            #pragma unroll
            for (int j = 0; j < 16; j++){
                float wv = s_w2[i*16 + j];
                h2a[j] = fmaf(aa, wv, h2a[j]);
                h2b[j] = fmaf(ab, wv, h2b[j]);
            }
        }
        float sa = p2bv, sb = p2bv;
        #pragma unroll
        for (int j = 0; j < 16; j++){
            float pw = s_p2w[j];
            sa = fmaf(silu_f(h2a[j]), pw, sa);
            sb = fmaf(silu_f(h2b[j]), pw, sb);
        }
        scores[tp] = sa; scores[tp+1] = sb;
    }

    float c0r[TBT], c1r[TBT];
    {
        float u10 = s_u1[0], u11 = s_u1[1];
        float w00 = s_w21[0], w01 = s_w21[1], w10 = s_w21[2], w11 = s_w21[3];
        float b0 = s_b21[0], b1 = s_b21[1];
        #pragma unroll
        for (int ti = 0; ti < TBT; ti++){
            float gl0 = silu_f(fmaf(tv[ti], u10, v1r0));
            float gl1 = silu_f(fmaf(tv[ti], u11, v1r1));
            c0r[ti] = silu_f(fmaf(gl0, w00, fmaf(gl1, w10, b0)));
            c1r[ti] = silu_f(fmaf(gl0, w01, fmaf(gl1, w11, b1)));
        }
    }

    float m[TBT];
    #pragma unroll
    for (int ti = 0; ti < TBT; ti++) m[ti] = scores[ti];
    #pragma unroll
    for (int off = 32; off; off >>= 1){
        #pragma unroll
        for (int ti = 0; ti < TBT; ti++) m[ti] = fmaxf(m[ti], __shfl_xor(m[ti], off));
    }
    if (lane == 0){
        #pragma unroll
        for (int ti = 0; ti < TBT; ti++) s_xa[wave][ti] = m[ti];
    }
    __syncthreads();
    #pragma unroll
    for (int ti = 0; ti < TBT; ti++)
        m[ti] = fmaxf(fmaxf(s_xa[0][ti], s_xa[1][ti]), fmaxf(s_xa[2][ti], s_xa[3][ti]));

    float e[TBT], ps[TBT], pc0[TBT], pc1[TBT];
    #pragma unroll
    for (int ti = 0; ti < TBT; ti++){
        e[ti]  = __expf(scores[ti] - m[ti]);
        ps[ti] = e[ti];
        pc0[ti] = e[ti] * c0r[ti];
        pc1[ti] = e[ti] * c1r[ti];
    }
    #pragma unroll
    for (int off = 32; off; off >>= 1){
        #pragma unroll
        for (int ti = 0; ti < TBT; ti++){
            ps[ti]  += __shfl_xor(ps[ti],  off);
            pc0[ti] += __shfl_xor(pc0[ti], off);
            pc1[ti] += __shfl_xor(pc1[ti], off);
        }
    }
    if (lane == 0){
        #pragma unroll
        for (int ti = 0; ti < TBT; ti++){
            s_xs[wave][ti]  = ps[ti];
            s_xc0[wave][ti] = pc0[ti];
            s_xc1[wave][ti] = pc1[ti];
        }
    }
    __syncthreads();
    #pragma unroll
    for (int ti = 0; ti < TBT; ti++){
        float S  = s_xs[0][ti] + s_xs[1][ti] + s_xs[2][ti] + s_xs[3][ti];
        float rS = fast_rcp(S);
        s_wsmT[w][ti] = e[ti] * rS;
    }
    if (tid < TBT){
        int ti = tid;
        float S  = s_xs[0][ti] + s_xs[1][ti] + s_xs[2][ti] + s_xs[3][ti];
        float rS = fast_rcp(S);
        s_wc0[ti] = (s_xc0[0][ti] + s_xc0[1][ti] + s_xc0[2][ti] + s_xc0[3][ti]) * rS;
        s_wc1[ti] = (s_xc1[0][ti] + s_xc1[1][ti] + s_xc1[2][ti] + s_xc1[3][ti]) * rS;
    }
    __syncthreads();

    int wid = wave;
    int dq  = lane;
    const float* fbase = feat + (size_t)n*WT*DIM + dq*4;
    float4 acc[TBT];
    #pragma unroll
    for (int i = 0; i < TBT; i++) acc[i] = make_float4(0.f, 0.f, 0.f, 0.f);

    #pragma unroll 4
    for (int w0 = wid; w0 < WT; w0 += 4){
        float4 f = *(const float4*)(fbase + (size_t)w0*DIM);
        const float4* wp = (const float4*)&s_wsmT[w0][0];
        float4 wA = wp[0], wB = wp[1];
        fma4(acc[0], wA.x, f); fma4(acc[1], wA.y, f);
        fma4(acc[2], wA.z, f); fma4(acc[3], wA.w, f);
        fma4(acc[4], wB.x, f); fma4(acc[5], wB.y, f);
        fma4(acc[6], wB.z, f); fma4(acc[7], wB.w, f);
    }

    float pw0 = p1w[tid], pw1 = p1w[DIM + tid], pbv = p1b[tid];
    float* orow = out + ((size_t)n*TT + t0)*DIM;
    #pragma unroll
    for (int ti = 0; ti < TBT; ti++){
        __syncthreads();
        *(float4*)&s_out[wid][dq*4] = acc[ti];
        __syncthreads();
        float r = s_out[0][tid] + s_out[1][tid] + s_out[2][tid] + s_out[3][tid];
        float o = fmaf(s_wc0[ti], pw0, fmaf(s_wc1[ti], pw1, r + pbv));
        orow[(size_t)ti*DIM + tid] = o;
    }
}

extern "C" void kernel_launch(void* const* d_in, const int* in_sizes, int n_in,
                              void* d_out, int out_size, void* d_ws, size_t ws_size,
                              hipStream_t stream)
{
    const float* Tg    = (const float*)d_in[0];
    const float* dur   = (const float*)d_in[1];
    const float* feat  = (const float*)d_in[2];
    const float* c1w   = (const float*)d_in[3];
    const float* c1b   = (const float*)d_in[4];
    const float* bn1g  = (const float*)d_in[5];
    const float* bn1b  = (const float*)d_in[6];
    const float* bn1m  = (const float*)d_in[7];
    const float* bn1v  = (const float*)d_in[8];
    const float* c2w   = (const float*)d_in[9];
    const float* c2b   = (const float*)d_in[10];
    const float* bn2g  = (const float*)d_in[11];
    const float* bn2b  = (const float*)d_in[12];
    const float* bn2m  = (const float*)d_in[13];
    const float* bn2v  = (const float*)d_in[14];
    const float* sb1w1 = (const float*)d_in[15];
    const float* sb1b1 = (const float*)d_in[16];
    const float* sb1w2 = (const float*)d_in[17];
    const float* sb1b2 = (const float*)d_in[18];
    const float* sb2w1 = (const float*)d_in[19];
    const float* sb2b1 = (const float*)d_in[20];
    const float* sb2w2 = (const float*)d_in[21];
    const float* sb2b2 = (const float*)d_in[22];
    const float* p1w   = (const float*)d_in[23];
    const float* p1b   = (const float*)d_in[24];
    const float* p2w   = (const float*)d_in[25];
    const float* p2b   = (const float*)d_in[26];
    float* out = (float*)d_out;

    // ws layout (float units): v1[8192] v2[65536] wc[65536]
    // then bf16 arrays: wsmB[NN*TT*WT] featP[NN*WT*DIM]
    float* ws = (float*)d_ws;
    float* v1  = ws;
    float* v2  = ws + 8192;
    float* wc  = ws + 8192 + 65536;
    unsigned short* wsmB  = (unsigned short*)(ws + 8192 + 65536 + 65536);
    unsigned short* featP = wsmB + (size_t)NN*TT*WT;
    size_t need = ((size_t)8192 + 65536 + 65536)*sizeof(float)
                + ((size_t)NN*TT*WT + (size_t)NN*WT*DIM)*sizeof(unsigned short);

    prep_k<<<dim3(WT, NN), 256, 0, stream>>>(dur, feat, c1w, c1b, bn1g, bn1b, bn1m, bn1v,
                                             c2w, c2b, bn2g, bn2b, bn2m, bn2v,
                                             sb1w1, sb1b1, sb2w1, sb2b1, v1, v2);
    if (ws_size >= need){
        featpack_k<<<dim3(8, NN), 256, 0, stream>>>(feat, featP);
        score_k<<<dim3(TT/TBT, NN), 256, 0, stream>>>(Tg, v1, v2,
                                                      sb1w1, sb1w2, sb1b2,
                                                      sb2w1, sb2w2, sb2b2,
                                                      p2w, p2b, wsmB, wc);
        outr_mfma_k<<<dim3(TT/32, NN), 512, 0, stream>>>(wsmB, featP, wc, p1w, p1b, out);
    } else {
        fused_k<<<dim3(TT/TBT, NN), 256, 0, stream>>>(Tg, feat, v1, v2,
                                                      sb1w1, sb1w2, sb1b2,
                                                      sb2w1, sb2w2, sb2b2,
                                                      p1w, p1b, p2w, p2b, out);
    }
}

// Round 10
// 258.955 us; speedup vs baseline: 1.2075x; 1.0721x over previous
//
#include <hip/hip_runtime.h>
#include <hip/hip_bf16.h>

#define NN  16
#define WT  256
#define TT  2048
#define DIM 256
#define TBT 8      // t-values per block in score kernel
#define RSTR 260   // padded row stride (floats) for reduce LDS: spreads ti across banks

typedef __attribute__((ext_vector_type(8))) short short8_t;  // 8 bf16 (4 VGPRs)
typedef __attribute__((ext_vector_type(4))) float f32x4;     // MFMA acc

__device__ __forceinline__ float fast_rcp(float x){ return __builtin_amdgcn_rcpf(x); }

__device__ __forceinline__ float silu_f(float x){
    return x * fast_rcp(1.0f + __expf(-x));
}

__device__ __forceinline__ unsigned short f2bf(float x){
    union { float f; unsigned u; } v; v.f = x;
    unsigned r = v.u + 0x7FFFu + ((v.u >> 16) & 1u);   // round-to-nearest-even
    return (unsigned short)(r >> 16);
}

__device__ __forceinline__ void fma4(float4& a, float s, const float4& f){
    a.x = fmaf(s, f.x, a.x); a.y = fmaf(s, f.y, a.y);
    a.z = fmaf(s, f.z, a.z); a.w = fmaf(s, f.w, a.w);
}

// ------- Kernel B: cumsum (in-block scan) + conv(3,256->8)+BN+SiLU, fold into v1/v2 -------
__global__ __launch_bounds__(256) void prep_k(
    const float* __restrict__ dur, const float* __restrict__ feat,
    const float* __restrict__ c1w, const float* __restrict__ c1b,
    const float* __restrict__ g1,  const float* __restrict__ be1,
    const float* __restrict__ m1,  const float* __restrict__ vv1,
    const float* __restrict__ c2w, const float* __restrict__ c2b,
    const float* __restrict__ g2,  const float* __restrict__ be2,
    const float* __restrict__ m2,  const float* __restrict__ vv2,
    const float* __restrict__ sb1w1, const float* __restrict__ sb1b1,
    const float* __restrict__ sb2w1, const float* __restrict__ sb2b1,
    float* __restrict__ v1o, float* __restrict__ v2o)
{
    int w = blockIdx.x, n = blockIdx.y;
    int tid = threadIdx.x;              // channel c

    // ---- in-block inclusive scan of durations for this n ----
    __shared__ float sdur[WT];
    sdur[tid] = dur[n*WT + tid];
    __syncthreads();
    for (int off = 1; off < WT; off <<= 1){
        float v = (tid >= off) ? sdur[tid-off] : 0.0f;
        __syncthreads();
        sdur[tid] += v;
        __syncthreads();
    }
    float end   = sdur[w];              // broadcast read
    float start = end - dur[n*WT + w];  // uniform scalar load

    const float* fb = feat + (size_t)(n*WT)*DIM;
    float fm = (w > 0)    ? fb[(size_t)(w-1)*DIM + tid] : 0.0f;
    float f0 =              fb[(size_t) w   *DIM + tid];
    float fp = (w < WT-1) ? fb[(size_t)(w+1)*DIM + tid] : 0.0f;

    float pl[8], pr[8];
    #pragma unroll
    for (int o = 0; o < 8; o++){
        const float* wp = c1w + (size_t)(o*DIM + tid)*3;
        pl[o] = fmaf(fm, wp[0], fmaf(f0, wp[1], fp*wp[2]));
        const float* wq = c2w + (size_t)(o*DIM + tid)*3;
        pr[o] = fmaf(fm, wq[0], fmaf(f0, wq[1], fp*wq[2]));
    }
    #pragma unroll
    for (int o = 0; o < 8; o++){
        #pragma unroll
        for (int off = 32; off; off >>= 1){
            pl[o] += __shfl_xor(pl[o], off);
            pr[o] += __shfl_xor(pr[o], off);
        }
    }
    __shared__ float sws[4][16];
    int wave = tid >> 6, lane = tid & 63;
    if (lane == 0){
        #pragma unroll
        for (int o = 0; o < 8; o++){ sws[wave][o] = pl[o]; sws[wave][8+o] = pr[o]; }
    }
    __syncthreads();
    __shared__ float slr[16];   // [0..7]=left(SiLU'd), [8..15]=right
    if (tid < 16){
        float s = sws[0][tid] + sws[1][tid] + sws[2][tid] + sws[3][tid];
        int o = tid & 7; bool isr = tid >= 8;
        float bias = isr ? c2b[o] : c1b[o];
        float mm   = isr ? m2[o]  : m1[o];
        float vv   = isr ? vv2[o] : vv1[o];
        float gg   = isr ? g2[o]  : g1[o];
        float bb   = isr ? be2[o] : be1[o];
        float y = s + bias;
        y = (y - mm) * rsqrtf(vv + 1e-5f);
        y = y * gg + bb;
        slr[tid] = silu_f(y);
    }
    __syncthreads();
    if (tid < 16){
        int j = tid;
        float acc = sb2b1[j] - start*sb2w1[j] + end*sb2w1[16 + j];
        #pragma unroll
        for (int o = 0; o < 8; o++) acc = fmaf(slr[8+o], sb2w1[(2+o)*16 + j], acc);
        v2o[(size_t)(n*WT + w)*16 + j] = acc;
    } else if (tid < 18){
        int p = tid - 16;
        float acc = sb1b1[p] - start*sb1w1[p] + end*sb1w1[2 + p];
        #pragma unroll
        for (int o = 0; o < 8; o++) acc = fmaf(slr[o], sb1w1[(2+o)*2 + p], acc);
        v1o[(size_t)(n*WT + w)*2 + p] = acc;
    }
}

// ------- Kernel B2: pack feat into B-fragment bf16 layout [n][w/32][d][w%32] -------
__global__ __launch_bounds__(256) void featpack_k(const float* __restrict__ feat,
                                                  unsigned short* __restrict__ featP)
{
    int kb = blockIdx.x, n = blockIdx.y;   // kb = 0..7 (k-block of 32 w's)
    int d = threadIdx.x;
    const float* fb = feat + (size_t)n*WT*DIM + (size_t)kb*32*DIM + d;
    unsigned short* op = featP + ((size_t)(n*8 + kb)*DIM + d)*32;
    unsigned short buf[32];
    #pragma unroll
    for (int e = 0; e < 32; e++) buf[e] = f2bf(fb[(size_t)e*DIM]);   // coalesced reads
    #pragma unroll
    for (int g = 0; g < 4; g++){
        uint4 u;
        u.x = (unsigned)buf[g*8+0] | ((unsigned)buf[g*8+1] << 16);
        u.y = (unsigned)buf[g*8+2] | ((unsigned)buf[g*8+3] << 16);
        u.z = (unsigned)buf[g*8+4] | ((unsigned)buf[g*8+5] << 16);
        u.w = (unsigned)buf[g*8+6] | ((unsigned)buf[g*8+7] << 16);
        *(uint4*)(op + g*8) = u;
    }
}

// ---------------- Kernel C1: scores -> softmax weights (bf16, to global ws) ----------------
// R16 = session-best tier body + LDS-TRANSPOSE REDUCE.  The old softmax used
// 192 __shfl_xor per thread (6 levels x 8 ti x [max + 3 sums]) -- these lower to
// ds_swizzle/ds_bpermute: LDS-PIPE ops invisible to VALUBusy.  Arithmetic:
// 16 blk/CU x 4 waves x 192 x ~5.8cyc ~= 30us/CU of DS serialization -- the
// hidden co-critical path that pinned score_k at ~123us while VALU work halved
// (R0 94% busy -> R2 47%).  New reduce: write values to s_red[a][ti][w]
// (stride-1 b32, conflict-free), barrier, 8 threads/job read 32 contiguous
// floats as rotated b128 chunks (rotation (o+ch)&7 -> conflict-free), 3-level
// 8-lane shuffle, broadcast via s_sum.  ~55 DS ops/thread vs 192.
// Tier code / c-path / other kernels byte-identical to session best.
__global__ __launch_bounds__(256) void score_k(
    const float* __restrict__ Tg,
    const float* __restrict__ v1g, const float* __restrict__ v2g,
    const float* __restrict__ sb1w1, const float* __restrict__ sb1w2, const float* __restrict__ sb1b2,
    const float* __restrict__ sb2w1, const float* __restrict__ sb2w2, const float* __restrict__ sb2b2,
    const float* __restrict__ p2w, const float* __restrict__ p2b,
    unsigned short* __restrict__ wsm_b, float* __restrict__ wc_g)
{
    int n   = blockIdx.y;
    int t0  = blockIdx.x * TBT;
    int tid = threadIdx.x;
    int w   = tid;
    int lane = tid & 63, wave = tid >> 6;

    __shared__ float s_w2[16*16];
    __shared__ float s_u2[16], s_b2[16], s_p2w[16];
    __shared__ float s_u1[2], s_w21[4], s_b21[2];
    __shared__ __align__(16) float s_red[3][TBT][RSTR];   // 24.4 KB reduce scratch
    __shared__ float s_sum[3][TBT];
    __shared__ float s_mx[TBT];

    s_w2[tid] = sb2w2[tid];
    if (tid < 16){
        s_u2[tid]  = sb2w1[tid] - sb2w1[16 + tid];
        s_b2[tid]  = sb2b2[tid];
        s_p2w[tid] = p2w[tid];
    } else if (tid < 18){
        int p = tid - 16;
        s_u1[p]  = sb1w1[p] - sb1w1[2 + p];
        s_b21[p] = sb1b2[p];
    } else if (tid < 22){
        s_w21[tid - 18] = sb1w2[tid - 18];
    }
    __syncthreads();

    float v2r[16];
    {
        const float4* vp = (const float4*)(v2g + (size_t)(n*WT + w)*16);
        float4 a = vp[0], b = vp[1], c = vp[2], d = vp[3];
        v2r[0]=a.x; v2r[1]=a.y; v2r[2]=a.z; v2r[3]=a.w;
        v2r[4]=b.x; v2r[5]=b.y; v2r[6]=b.z; v2r[7]=b.w;
        v2r[8]=c.x; v2r[9]=c.y; v2r[10]=c.z; v2r[11]=c.w;
        v2r[12]=d.x; v2r[13]=d.y; v2r[14]=d.z; v2r[15]=d.w;
    }
    float v1r0, v1r1;
    {
        const float* vp = v1g + (size_t)(n*WT + w)*2;
        v1r0 = vp[0]; v1r1 = vp[1];
    }
    float p2bv = p2b[0];
    float tv[TBT];
    #pragma unroll
    for (int ti = 0; ti < TBT; ti++) tv[ti] = Tg[t0 + ti];

    // ---- classify saturation of each a_i over this block's t-window ----
    unsigned mpos = 0u, mneg = 0u;
    #pragma unroll
    for (int i = 0; i < 16; i++){
        float u = s_u2[i], v = v2r[i];
        float xa = fmaf(tv[0],     u, v);
        float xb = fmaf(tv[TBT-1], u, v);
        float lo = fminf(xa, xb), hi = fmaxf(xa, xb);
        if (__all(lo >  20.0f)) mpos |= (1u << i);
        else if (__all(hi < -20.0f)) mneg |= (1u << i);
    }
    unsigned mact = 0xFFFFu & ~(mpos | mneg);

    float scores[TBT];
    if (mact == 0u){
        // -------- fast tier: all i saturated -> h_j exactly linear in t --------
        float hA[16], hB[16];
        #pragma unroll
        for (int j = 0; j < 16; j++){ hA[j] = s_b2[j]; hB[j] = 0.0f; }
        #pragma unroll
        for (int i = 0; i < 16; i++){
            if (mpos & (1u << i)){          // wave-uniform scalar branch
                float u = s_u2[i], v = v2r[i];
                #pragma unroll
                for (int j = 0; j < 16; j++){
                    float wv = s_w2[i*16 + j];
                    hA[j] = fmaf(v, wv, hA[j]);
                    hB[j] = fmaf(u, wv, hB[j]);
                }
            }
        }
        // classify j's from endpoints (exact: h_j linear in t), fold pos-j's
        unsigned jact = 0u;
        float SA = p2bv, SB = 0.0f;
        #pragma unroll
        for (int j = 0; j < 16; j++){
            float h0 = fmaf(tv[0],     hB[j], hA[j]);
            float h7 = fmaf(tv[TBT-1], hB[j], hA[j]);
            float lo = fminf(h0, h7), hi = fmaxf(h0, h7);
            float pw = s_p2w[j];
            if (__all(lo > 20.0f)){
                SA = fmaf(hA[j], pw, SA);
                SB = fmaf(hB[j], pw, SB);
            } else if (!__all(hi < -20.0f)){
                jact |= (1u << j);
            }
        }
        if (jact == 0u){
            #pragma unroll
            for (int ti = 0; ti < TBT; ti++) scores[ti] = fmaf(tv[ti], SB, SA);
        } else {
            #pragma unroll
            for (int ti = 0; ti < TBT; ti++){
                float s = fmaf(tv[ti], SB, SA);
                #pragma unroll
                for (int j = 0; j < 16; j++){
                    if (jact & (1u << j))
                        s = fmaf(silu_f(fmaf(tv[ti], hB[j], hA[j])), s_p2w[j], s);
                }
                scores[ti] = s;
            }
        }
    } else {
        // -------- slow tier: per-pair path (tested) --------
        #pragma unroll
        for (int tp = 0; tp < TBT; tp += 2){
            float h2a[16], h2b[16];
            #pragma unroll
            for (int j = 0; j < 16; j++){ float b = s_b2[j]; h2a[j] = b; h2b[j] = b; }
            #pragma unroll
            for (int i = 0; i < 16; i++){
                if (mneg & (1u << i)) continue;           // a == 0: skip fan-out
                float u = s_u2[i], v = v2r[i];
                float aa = fmaf(tv[tp],   u, v);
                float ab = fmaf(tv[tp+1], u, v);
                if (!(mpos & (1u << i))){                 // not linear-saturated
                    aa = silu_f(aa);
                    ab = silu_f(ab);
                }
                #pragma unroll
                for (int j = 0; j < 16; j++){
                    float wv = s_w2[i*16 + j];
                    h2a[j] = fmaf(aa, wv, h2a[j]);
                    h2b[j] = fmaf(ab, wv, h2b[j]);
                }
            }
            float sa = p2bv, sb = p2bv;
            #pragma unroll
            for (int j = 0; j < 16; j++){
                float pw = s_p2w[j];
                float ha = h2a[j], hb = h2b[j];
                if (__all(fminf(ha, hb) > 20.0f)){
                    sa = fmaf(ha, pw, sa);
                    sb = fmaf(hb, pw, sb);
                } else if (__all(fmaxf(ha, hb) < -20.0f)){
                    // silu(h) ~ 0: no contribution
                } else {
                    sa = fmaf(silu_f(ha), pw, sa);
                    sb = fmaf(silu_f(hb), pw, sb);
                }
            }
            scores[tp] = sa; scores[tp+1] = sb;
        }
    }

    float c0r[TBT], c1r[TBT];
    {
        float u10 = s_u1[0], u11 = s_u1[1];
        float w00 = s_w21[0], w01 = s_w21[1], w10 = s_w21[2], w11 = s_w21[3];
        float b0 = s_b21[0], b1 = s_b21[1];
        // classify gl0/gl1 over the block window (same monotone-endpoint trick)
        float x0a = fmaf(tv[0], u10, v1r0), x0b = fmaf(tv[TBT-1], u10, v1r0);
        float x1a = fmaf(tv[0], u11, v1r1), x1b = fmaf(tv[TBT-1], u11, v1r1);
        bool p0 = __all(fminf(x0a, x0b) >  20.0f);
        bool n0 = __all(fmaxf(x0a, x0b) < -20.0f);
        bool p1 = __all(fminf(x1a, x1b) >  20.0f);
        bool n1 = __all(fmaxf(x1a, x1b) < -20.0f);
        #pragma unroll
        for (int ti = 0; ti < TBT; ti++){
            float x0 = fmaf(tv[ti], u10, v1r0);
            float x1 = fmaf(tv[ti], u11, v1r1);
            float gl0, gl1;
            if (p0)      gl0 = x0;
            else if (n0) gl0 = 0.0f;
            else         gl0 = silu_f(x0);
            if (p1)      gl1 = x1;
            else if (n1) gl1 = 0.0f;
            else         gl1 = silu_f(x1);
            float y0 = fmaf(gl0, w00, fmaf(gl1, w10, b0));
            float y1 = fmaf(gl0, w01, fmaf(gl1, w11, b1));
            if (__all(fminf(y0, y1) > 20.0f)){
                c0r[ti] = y0; c1r[ti] = y1;
            } else if (__all(fmaxf(y0, y1) < -20.0f)){
                c0r[ti] = 0.0f; c1r[ti] = 0.0f;
            } else {
                c0r[ti] = silu_f(y0); c1r[ti] = silu_f(y1);
            }
        }
    }

    // ================= LDS-transpose reduce (replaces 192 shuffles) =================
    // --- max over w for each ti ---
    #pragma unroll
    for (int ti = 0; ti < TBT; ti++) s_red[0][ti][w] = scores[ti];   // stride-1: conflict-free
    __syncthreads();
    if (wave == 0){
        int ti = lane >> 3, ch = lane & 7;
        const float4* rp = (const float4*)&s_red[0][ti][ch*32];
        float mx = -3.402823466e38f;
        #pragma unroll
        for (int oo = 0; oo < 8; oo++){
            int o = (oo + ch) & 7;        // rotation -> per-step distinct banks
            float4 v = rp[o];
            mx = fmaxf(mx, fmaxf(fmaxf(v.x, v.y), fmaxf(v.z, v.w)));
        }
        mx = fmaxf(mx, __shfl_xor(mx, 1));
        mx = fmaxf(mx, __shfl_xor(mx, 2));
        mx = fmaxf(mx, __shfl_xor(mx, 4));
        if (ch == 0) s_mx[ti] = mx;
    }
    __syncthreads();

    float e[TBT];
    #pragma unroll
    for (int ti = 0; ti < TBT; ti++){
        e[ti] = __expf(scores[ti] - s_mx[ti]);     // broadcast read: conflict-free
        s_red[0][ti][w] = e[ti];
        s_red[1][ti][w] = e[ti] * c0r[ti];
        s_red[2][ti][w] = e[ti] * c1r[ti];
    }
    __syncthreads();
    if (wave < 3){
        int ti = lane >> 3, ch = lane & 7;
        const float4* rp = (const float4*)&s_red[wave][ti][ch*32];
        float s = 0.0f;
        #pragma unroll
        for (int oo = 0; oo < 8; oo++){
            int o = (oo + ch) & 7;
            float4 v = rp[o];
            s += (v.x + v.y) + (v.z + v.w);
        }
        s += __shfl_xor(s, 1);
        s += __shfl_xor(s, 2);
        s += __shfl_xor(s, 4);
        if (ch == 0) s_sum[wave][ti] = s;
    }
    __syncthreads();

    unsigned short* wbase = wsm_b + ((size_t)n*TT + t0)*WT + w;
    #pragma unroll
    for (int ti = 0; ti < TBT; ti++){
        float rS = fast_rcp(s_sum[0][ti]);         // broadcast read
        wbase[(size_t)ti*WT] = f2bf(e[ti] * rS);
    }
    if (tid < TBT){
        int ti = tid;
        float rS = fast_rcp(s_sum[0][ti]);
        float2 wc;
        wc.x = s_sum[1][ti] * rS;
        wc.y = s_sum[2][ti] * rS;
        *(float2*)(wc_g + ((size_t)n*TT + t0 + ti)*2) = wc;
    }
}

// ---------------- Kernel C2: out_r via bf16 MFMA GEMM + epilogue (R7 form) ----------------
__global__ __launch_bounds__(512) void outr_mfma_k(
    const unsigned short* __restrict__ wsmB, const unsigned short* __restrict__ featP,
    const float* __restrict__ wc_g,
    const float* __restrict__ p1w, const float* __restrict__ p1b,
    float* __restrict__ out)
{
    int n    = blockIdx.y;
    int t0   = blockIdx.x * 32;
    int tid  = threadIdx.x;
    int lane = tid & 63, wave = tid >> 6;
    int tw   = t0 + (wave >> 2) * 16;    // waves 0-3 -> t0, 4-7 -> t0+16
    int dbase = (wave & 3) * 4;          // 4 dt-blocks (64 d) per wave
    int l15  = lane & 15, quad = lane >> 4;

    f32x4 acc[4];
    #pragma unroll
    for (int dt = 0; dt < 4; dt++) acc[dt] = (f32x4){0.f, 0.f, 0.f, 0.f};

    const unsigned short* aPtr = wsmB + ((size_t)(n*TT + tw + l15))*WT + quad*8;

    #pragma unroll
    for (int kb = 0; kb < 8; kb++){
        short8_t af = *(const short8_t*)(aPtr + kb*32);
        const unsigned short* bp = featP + ((size_t)(n*8 + kb)*DIM + dbase*16 + l15)*32 + quad*8;
        #pragma unroll
        for (int dt = 0; dt < 4; dt++){
            short8_t bf = *(const short8_t*)(bp + (size_t)dt*16*32);
            acc[dt] = __builtin_amdgcn_mfma_f32_16x16x32_bf16(af, bf, acc[dt], 0, 0, 0);
        }
    }

    float wc0[4], wc1[4];
    #pragma unroll
    for (int r = 0; r < 4; r++){
        const float* wp = wc_g + ((size_t)(n*TT + tw + quad*4 + r))*2;
        wc0[r] = wp[0]; wc1[r] = wp[1];
    }
    float* obase = out + ((size_t)(n*TT + tw + quad*4))*DIM;
    #pragma unroll
    for (int dt = 0; dt < 4; dt++){
        int d = (dbase + dt)*16 + l15;   // D col
        float pa = p1w[d], pb2 = p1w[DIM + d], pc = p1b[d];
        #pragma unroll
        for (int r = 0; r < 4; r++){     // D row = quad*4 + r
            float val = acc[dt][r] + fmaf(wc0[r], pa, fmaf(wc1[r], pb2, pc));
            obase[(size_t)r*DIM + d] = val;
        }
    }
}

// ---------------- Fallback fused kernel (R1, known-good) if ws too small ----------------
__global__ __launch_bounds__(256) void fused_k(
    const float* __restrict__ Tg, const float* __restrict__ feat,
    const float* __restrict__ v1g, const float* __restrict__ v2g,
    const float* __restrict__ sb1w1, const float* __restrict__ sb1w2, const float* __restrict__ sb1b2,
    const float* __restrict__ sb2w1, const float* __restrict__ sb2w2, const float* __restrict__ sb2b2,
    const float* __restrict__ p1w, const float* __restrict__ p1b,
    const float* __restrict__ p2w, const float* __restrict__ p2b,
    float* __restrict__ out)
{
    int n   = blockIdx.y;
    int t0  = blockIdx.x * TBT;
    int tid = threadIdx.x;
    int w   = tid;
    int lane = tid & 63, wave = tid >> 6;

    __shared__ float s_w2[16*16];
    __shared__ float s_u2[16], s_b2[16], s_p2w[16];
    __shared__ float s_u1[2], s_w21[4], s_b21[2];
    __shared__ float s_wsmT[WT][TBT];
    __shared__ float s_xa[4][TBT];
    __shared__ float s_xs[4][TBT];
    __shared__ float s_xc0[4][TBT], s_xc1[4][TBT];
    __shared__ float s_wc0[TBT], s_wc1[TBT];
    __shared__ float s_out[4][DIM];

    s_w2[tid] = sb2w2[tid];
    if (tid < 16){
        s_u2[tid]  = sb2w1[tid] - sb2w1[16 + tid];
        s_b2[tid]  = sb2b2[tid];
        s_p2w[tid] = p2w[tid];
    } else if (tid < 18){
        int p = tid - 16;
        s_u1[p]  = sb1w1[p] - sb1w1[2 + p];
        s_b21[p] = sb1b2[p];
    } else if (tid < 22){
        s_w21[tid - 18] = sb1w2[tid - 18];
    }
    __syncthreads();

    float v2r[16];
    {
        const float4* vp = (const float4*)(v2g + (size_t)(n*WT + w)*16);
        float4 a = vp[0], b = vp[1], c = vp[2], d = vp[3];
        v2r[0]=a.x; v2r[1]=a.y; v2r[2]=a.z; v2r[3]=a.w;
        v2r[4]=b.x; v2r[5]=b.y; v2r[6]=b.z; v2r[7]=b.w;
        v2r[8]=c.x; v2r[9]=c.y; v2r[10]=c.z; v2r[11]=c.w;
        v2r[12]=d.x; v2r[13]=d.y; v2r[14]=d.z; v2r[15]=d.w;
    }
    float v1r0, v1r1;
    {
        const float* vp = v1g + (size_t)(n*WT + w)*2;
        v1r0 = vp[0]; v1r1 = vp[1];
    }
    float p2bv = p2b[0];
    float tv[TBT];
    #pragma unroll
    for (int ti = 0; ti < TBT; ti++) tv[ti] = Tg[t0 + ti];

    float scores[TBT];
    #pragma unroll
    for (int tp = 0; tp < TBT; tp += 2){
        float h2a[16], h2b[16];
        #pragma unroll
        for (int j = 0; j < 16; j++){ float b = s_b2[j]; h2a[j] = b; h2b[j] = b; }
        #pragma unroll
        for (int i = 0; i < 16; i++){
            float u = s_u2[i], v = v2r[i];
            float aa = silu_f(fmaf(tv[tp],   u, v));
            float ab = silu_f(fmaf(tv[tp+1], u, v));
            #pragma unroll
            for (int j = 0; j < 16; j++){
                float wv = s_w2[i*16 + j];
                h2a[j] = fmaf(aa, wv, h2a[j]);
                h2b[j] = fmaf(ab, wv, h2b[j]);
            }
        }
        float sa = p2bv, sb = p2bv;
        #pragma unroll
        for (int j = 0; j < 16; j++){
            float pw = s_p2w[j];
            sa = fmaf(silu_f(h2a[j]), pw, sa);
            sb = fmaf(silu_f(h2b[j]), pw, sb);
        }
        scores[tp] = sa; scores[tp+1] = sb;
    }

    float c0r[TBT], c1r[TBT];
    {
        float u10 = s_u1[0], u11 = s_u1[1];
        float w00 = s_w21[0], w01 = s_w21[1], w10 = s_w21[2], w11 = s_w21[3];
        float b0 = s_b21[0], b1 = s_b21[1];
        #pragma unroll
        for (int ti = 0; ti < TBT; ti++){
            float gl0 = silu_f(fmaf(tv[ti], u10, v1r0));
            float gl1 = silu_f(fmaf(tv[ti], u11, v1r1));
            c0r[ti] = silu_f(fmaf(gl0, w00, fmaf(gl1, w10, b0)));
            c1r[ti] = silu_f(fmaf(gl0, w01, fmaf(gl1, w11, b1)));
        }
    }

    float m[TBT];
    #pragma unroll
    for (int ti = 0; ti < TBT; ti++) m[ti] = scores[ti];
    #pragma unroll
    for (int off = 32; off; off >>= 1){
        #pragma unroll
        for (int ti = 0; ti < TBT; ti++) m[ti] = fmaxf(m[ti], __shfl_xor(m[ti], off));
    }
    if (lane == 0){
        #pragma unroll
        for (int ti = 0; ti < TBT; ti++) s_xa[wave][ti] = m[ti];
    }
    __syncthreads();
    #pragma unroll
    for (int ti = 0; ti < TBT; ti++)
        m[ti] = fmaxf(fmaxf(s_xa[0][ti], s_xa[1][ti]), fmaxf(s_xa[2][ti], s_xa[3][ti]));

    float e[TBT], ps[TBT], pc0[TBT], pc1[TBT];
    #pragma unroll
    for (int ti = 0; ti < TBT; ti++){
        e[ti]  = __expf(scores[ti] - m[ti]);
        ps[ti] = e[ti];
        pc0[ti] = e[ti] * c0r[ti];
        pc1[ti] = e[ti] * c1r[ti];
    }
    #pragma unroll
    for (int off = 32; off; off >>= 1){
        #pragma unroll
        for (int ti = 0; ti < TBT; ti++){
            ps[ti]  += __shfl_xor(ps[ti],  off);
            pc0[ti] += __shfl_xor(pc0[ti], off);
            pc1[ti] += __shfl_xor(pc1[ti], off);
        }
    }
    if (lane == 0){
        #pragma unroll
        for (int ti = 0; ti < TBT; ti++){
            s_xs[wave][ti]  = ps[ti];
            s_xc0[wave][ti] = pc0[ti];
            s_xc1[wave][ti] = pc1[ti];
        }
    }
    __syncthreads();
    #pragma unroll
    for (int ti = 0; ti < TBT; ti++){
        float S  = s_xs[0][ti] + s_xs[1][ti] + s_xs[2][ti] + s_xs[3][ti];
        float rS = fast_rcp(S);
        s_wsmT[w][ti] = e[ti] * rS;
    }
    if (tid < TBT){
        int ti = tid;
        float S  = s_xs[0][ti] + s_xs[1][ti] + s_xs[2][ti] + s_xs[3][ti];
        float rS = fast_rcp(S);
        s_wc0[ti] = (s_xc0[0][ti] + s_xc0[1][ti] + s_xc0[2][ti] + s_xc0[3][ti]) * rS;
        s_wc1[ti] = (s_xc1[0][ti] + s_xc1[1][ti] + s_xc1[2][ti] + s_xc1[3][ti]) * rS;
    }
    __syncthreads();

    int wid = wave;
    int dq  = lane;
    const float* fbase = feat + (size_t)n*WT*DIM + dq*4;
    float4 acc[TBT];
    #pragma unroll
    for (int i = 0; i < TBT; i++) acc[i] = make_float4(0.f, 0.f, 0.f, 0.f);

    #pragma unroll 4
    for (int w0 = wid; w0 < WT; w0 += 4){
        float4 f = *(const float4*)(fbase + (size_t)w0*DIM);
        const float4* wp = (const float4*)&s_wsmT[w0][0];
        float4 wA = wp[0], wB = wp[1];
        fma4(acc[0], wA.x, f); fma4(acc[1], wA.y, f);
        fma4(acc[2], wA.z, f); fma4(acc[3], wA.w, f);
        fma4(acc[4], wB.x, f); fma4(acc[5], wB.y, f);
        fma4(acc[6], wB.z, f); fma4(acc[7], wB.w, f);
    }

    float pw0 = p1w[tid], pw1 = p1w[DIM + tid], pbv = p1b[tid];
    float* orow = out + ((size_t)n*TT + t0)*DIM;
    #pragma unroll
    for (int ti = 0; ti < TBT; ti++){
        __syncthreads();
        *(float4*)&s_out[wid][dq*4] = acc[ti];
        __syncthreads();
        float r = s_out[0][tid] + s_out[1][tid] + s_out[2][tid] + s_out[3][tid];
        float o = fmaf(s_wc0[ti], pw0, fmaf(s_wc1[ti], pw1, r + pbv));
        orow[(size_t)ti*DIM + tid] = o;
    }
}

extern "C" void kernel_launch(void* const* d_in, const int* in_sizes, int n_in,
                              void* d_out, int out_size, void* d_ws, size_t ws_size,
                              hipStream_t stream)
{
    const float* Tg    = (const float*)d_in[0];
    const float* dur   = (const float*)d_in[1];
    const float* feat  = (const float*)d_in[2];
    const float* c1w   = (const float*)d_in[3];
    const float* c1b   = (const float*)d_in[4];
    const float* bn1g  = (const float*)d_in[5];
    const float* bn1b  = (const float*)d_in[6];
    const float* bn1m  = (const float*)d_in[7];
    const float* bn1v  = (const float*)d_in[8];
    const float* c2w   = (const float*)d_in[9];
    const float* c2b   = (const float*)d_in[10];
    const float* bn2g  = (const float*)d_in[11];
    const float* bn2b  = (const float*)d_in[12];
    const float* bn2m  = (const float*)d_in[13];
    const float* bn2v  = (const float*)d_in[14];
    const float* sb1w1 = (const float*)d_in[15];
    const float* sb1b1 = (const float*)d_in[16];
    const float* sb1w2 = (const float*)d_in[17];
    const float* sb1b2 = (const float*)d_in[18];
    const float* sb2w1 = (const float*)d_in[19];
    const float* sb2b1 = (const float*)d_in[20];
    const float* sb2w2 = (const float*)d_in[21];
    const float* sb2b2 = (const float*)d_in[22];
    const float* p1w   = (const float*)d_in[23];
    const float* p1b   = (const float*)d_in[24];
    const float* p2w   = (const float*)d_in[25];
    const float* p2b   = (const float*)d_in[26];
    float* out = (float*)d_out;

    // ws layout (float units): v1[8192] v2[65536] wc[65536]
    // then bf16 arrays: wsmB[NN*TT*WT] featP[NN*WT*DIM]
    float* ws = (float*)d_ws;
    float* v1  = ws;
    float* v2  = ws + 8192;
    float* wc  = ws + 8192 + 65536;
    unsigned short* wsmB  = (unsigned short*)(ws + 8192 + 65536 + 65536);
    unsigned short* featP = wsmB + (size_t)NN*TT*WT;
    size_t need = ((size_t)8192 + 65536 + 65536)*sizeof(float)
                + ((size_t)NN*TT*WT + (size_t)NN*WT*DIM)*sizeof(unsigned short);

    prep_k<<<dim3(WT, NN), 256, 0, stream>>>(dur, feat, c1w, c1b, bn1g, bn1b, bn1m, bn1v,
                                             c2w, c2b, bn2g, bn2b, bn2m, bn2v,
                                             sb1w1, sb1b1, sb2w1, sb2b1, v1, v2);
    if (ws_size >= need){
        featpack_k<<<dim3(8, NN), 256, 0, stream>>>(feat, featP);
        score_k<<<dim3(TT/TBT, NN), 256, 0, stream>>>(Tg, v1, v2,
                                                      sb1w1, sb1w2, sb1b2,
                                                      sb2w1, sb2w2, sb2b2,
                                                      p2w, p2b, wsmB, wc);
        outr_mfma_k<<<dim3(TT/32, NN), 512, 0, stream>>>(wsmB, featP, wc, p1w, p1b, out);
    } else {
        fused_k<<<dim3(TT/TBT, NN), 256, 0, stream>>>(Tg, feat, v1, v2,
                                                      sb1w1, sb1w2, sb1b2,
                                                      sb2w1, sb2w2, sb2b2,
                                                      p1w, p1b, p2w, p2b, out);
    }
}

// Round 11
// 256.706 us; speedup vs baseline: 1.2181x; 1.0088x over previous
//
#include <hip/hip_runtime.h>
#include <hip/hip_bf16.h>

#define NN  16
#define WT  256
#define TT  2048
#define DIM 256
#define TBT 8      // t-values per block in score kernel
#define RSTR 260   // padded row stride (floats) for reduce LDS: spreads ti across banks

typedef __attribute__((ext_vector_type(8))) short short8_t;  // 8 bf16 (4 VGPRs)
typedef __attribute__((ext_vector_type(4))) float f32x4;     // MFMA acc

__device__ __forceinline__ float fast_rcp(float x){ return __builtin_amdgcn_rcpf(x); }

__device__ __forceinline__ float silu_f(float x){
    return x * fast_rcp(1.0f + __expf(-x));
}

__device__ __forceinline__ unsigned short f2bf(float x){
    union { float f; unsigned u; } v; v.f = x;
    unsigned r = v.u + 0x7FFFu + ((v.u >> 16) & 1u);   // round-to-nearest-even
    return (unsigned short)(r >> 16);
}

__device__ __forceinline__ void fma4(float4& a, float s, const float4& f){
    a.x = fmaf(s, f.x, a.x); a.y = fmaf(s, f.y, a.y);
    a.z = fmaf(s, f.z, a.z); a.w = fmaf(s, f.w, a.w);
}

// ------- Kernel B: cumsum (in-block scan) + conv(3,256->8)+BN+SiLU, fold into v1/v2 -------
__global__ __launch_bounds__(256) void prep_k(
    const float* __restrict__ dur, const float* __restrict__ feat,
    const float* __restrict__ c1w, const float* __restrict__ c1b,
    const float* __restrict__ g1,  const float* __restrict__ be1,
    const float* __restrict__ m1,  const float* __restrict__ vv1,
    const float* __restrict__ c2w, const float* __restrict__ c2b,
    const float* __restrict__ g2,  const float* __restrict__ be2,
    const float* __restrict__ m2,  const float* __restrict__ vv2,
    const float* __restrict__ sb1w1, const float* __restrict__ sb1b1,
    const float* __restrict__ sb2w1, const float* __restrict__ sb2b1,
    float* __restrict__ v1o, float* __restrict__ v2o)
{
    int w = blockIdx.x, n = blockIdx.y;
    int tid = threadIdx.x;              // channel c

    // ---- in-block inclusive scan of durations for this n ----
    __shared__ float sdur[WT];
    sdur[tid] = dur[n*WT + tid];
    __syncthreads();
    for (int off = 1; off < WT; off <<= 1){
        float v = (tid >= off) ? sdur[tid-off] : 0.0f;
        __syncthreads();
        sdur[tid] += v;
        __syncthreads();
    }
    float end   = sdur[w];              // broadcast read
    float start = end - dur[n*WT + w];  // uniform scalar load

    const float* fb = feat + (size_t)(n*WT)*DIM;
    float fm = (w > 0)    ? fb[(size_t)(w-1)*DIM + tid] : 0.0f;
    float f0 =              fb[(size_t) w   *DIM + tid];
    float fp = (w < WT-1) ? fb[(size_t)(w+1)*DIM + tid] : 0.0f;

    float pl[8], pr[8];
    #pragma unroll
    for (int o = 0; o < 8; o++){
        const float* wp = c1w + (size_t)(o*DIM + tid)*3;
        pl[o] = fmaf(fm, wp[0], fmaf(f0, wp[1], fp*wp[2]));
        const float* wq = c2w + (size_t)(o*DIM + tid)*3;
        pr[o] = fmaf(fm, wq[0], fmaf(f0, wq[1], fp*wq[2]));
    }
    #pragma unroll
    for (int o = 0; o < 8; o++){
        #pragma unroll
        for (int off = 32; off; off >>= 1){
            pl[o] += __shfl_xor(pl[o], off);
            pr[o] += __shfl_xor(pr[o], off);
        }
    }
    __shared__ float sws[4][16];
    int wave = tid >> 6, lane = tid & 63;
    if (lane == 0){
        #pragma unroll
        for (int o = 0; o < 8; o++){ sws[wave][o] = pl[o]; sws[wave][8+o] = pr[o]; }
    }
    __syncthreads();
    __shared__ float slr[16];   // [0..7]=left(SiLU'd), [8..15]=right
    if (tid < 16){
        float s = sws[0][tid] + sws[1][tid] + sws[2][tid] + sws[3][tid];
        int o = tid & 7; bool isr = tid >= 8;
        float bias = isr ? c2b[o] : c1b[o];
        float mm   = isr ? m2[o]  : m1[o];
        float vv   = isr ? vv2[o] : vv1[o];
        float gg   = isr ? g2[o]  : g1[o];
        float bb   = isr ? be2[o] : be1[o];
        float y = s + bias;
        y = (y - mm) * rsqrtf(vv + 1e-5f);
        y = y * gg + bb;
        slr[tid] = silu_f(y);
    }
    __syncthreads();
    if (tid < 16){
        int j = tid;
        float acc = sb2b1[j] - start*sb2w1[j] + end*sb2w1[16 + j];
        #pragma unroll
        for (int o = 0; o < 8; o++) acc = fmaf(slr[8+o], sb2w1[(2+o)*16 + j], acc);
        v2o[(size_t)(n*WT + w)*16 + j] = acc;
    } else if (tid < 18){
        int p = tid - 16;
        float acc = sb1b1[p] - start*sb1w1[p] + end*sb1w1[2 + p];
        #pragma unroll
        for (int o = 0; o < 8; o++) acc = fmaf(slr[o], sb1w1[(2+o)*2 + p], acc);
        v1o[(size_t)(n*WT + w)*2 + p] = acc;
    }
}

// ------- Kernel B2: pack feat into B-fragment bf16 layout [n][w/32][d][w%32] -------
__global__ __launch_bounds__(256) void featpack_k(const float* __restrict__ feat,
                                                  unsigned short* __restrict__ featP)
{
    int kb = blockIdx.x, n = blockIdx.y;   // kb = 0..7 (k-block of 32 w's)
    int d = threadIdx.x;
    const float* fb = feat + (size_t)n*WT*DIM + (size_t)kb*32*DIM + d;
    unsigned short* op = featP + ((size_t)(n*8 + kb)*DIM + d)*32;
    unsigned short buf[32];
    #pragma unroll
    for (int e = 0; e < 32; e++) buf[e] = f2bf(fb[(size_t)e*DIM]);   // coalesced reads
    #pragma unroll
    for (int g = 0; g < 4; g++){
        uint4 u;
        u.x = (unsigned)buf[g*8+0] | ((unsigned)buf[g*8+1] << 16);
        u.y = (unsigned)buf[g*8+2] | ((unsigned)buf[g*8+3] << 16);
        u.z = (unsigned)buf[g*8+4] | ((unsigned)buf[g*8+5] << 16);
        u.w = (unsigned)buf[g*8+6] | ((unsigned)buf[g*8+7] << 16);
        *(uint4*)(op + g*8) = u;
    }
}

// ---------------- Kernel C1: scores -> softmax weights (bf16, to global ws) ----------------
// R17 = R16 (LDS-transpose reduce, confirmed +20us) + SCALAR-PATH WEIGHTS.
// R16 proved the DS pipe was co-critical (score_k 123->103, prediction matched).
// The remaining top DS consumer is the compute tiers' s_w2[i*16+j] broadcasts
// (256 ds_read/thread in the fold, up to 1024 in the slow tier).  All weights
// are BLOCK-UNIFORM with compile-time offsets -> read DIRECT from global:
// compiler emits s_load via the k-cache, touching neither VALU nor DS pipes;
// v_fmac_f32 v,s,v legally takes one SGPR operand.  (R0's note "SGPR weights
// regressed" was measured in the 94%-VALU-busy regime where DS time was hidden;
// regime is now DS+stall-bound at 50% busy -> mechanism visible.)
// LDS weight staging + its barrier deleted; reduce machinery identical to R16.
__global__ __launch_bounds__(256) void score_k(
    const float* __restrict__ Tg,
    const float* __restrict__ v1g, const float* __restrict__ v2g,
    const float* __restrict__ sb1w1, const float* __restrict__ sb1w2, const float* __restrict__ sb1b2,
    const float* __restrict__ sb2w1, const float* __restrict__ sb2w2, const float* __restrict__ sb2b2,
    const float* __restrict__ p2w, const float* __restrict__ p2b,
    unsigned short* __restrict__ wsm_b, float* __restrict__ wc_g)
{
    int n   = blockIdx.y;
    int t0  = blockIdx.x * TBT;
    int tid = threadIdx.x;
    int w   = tid;
    int lane = tid & 63, wave = tid >> 6;

    __shared__ __align__(16) float s_red[3][TBT][RSTR];   // 24.4 KB reduce scratch
    __shared__ float s_sum[3][TBT];
    __shared__ float s_mx[TBT];

    float v2r[16];
    {
        const float4* vp = (const float4*)(v2g + (size_t)(n*WT + w)*16);
        float4 a = vp[0], b = vp[1], c = vp[2], d = vp[3];
        v2r[0]=a.x; v2r[1]=a.y; v2r[2]=a.z; v2r[3]=a.w;
        v2r[4]=b.x; v2r[5]=b.y; v2r[6]=b.z; v2r[7]=b.w;
        v2r[8]=c.x; v2r[9]=c.y; v2r[10]=c.z; v2r[11]=c.w;
        v2r[12]=d.x; v2r[13]=d.y; v2r[14]=d.z; v2r[15]=d.w;
    }
    float v1r0, v1r1;
    {
        const float* vp = v1g + (size_t)(n*WT + w)*2;
        v1r0 = vp[0]; v1r1 = vp[1];
    }
    float p2bv = p2b[0];
    float tv[TBT];
    #pragma unroll
    for (int ti = 0; ti < TBT; ti++) tv[ti] = Tg[t0 + ti];

    // uniform u_i (scalar ALU; computed once)
    float u2r[16];
    #pragma unroll
    for (int i = 0; i < 16; i++) u2r[i] = sb2w1[i] - sb2w1[16 + i];

    // ---- classify saturation of each a_i over this block's t-window ----
    unsigned mpos = 0u, mneg = 0u;
    #pragma unroll
    for (int i = 0; i < 16; i++){
        float u = u2r[i], v = v2r[i];
        float xa = fmaf(tv[0],     u, v);
        float xb = fmaf(tv[TBT-1], u, v);
        float lo = fminf(xa, xb), hi = fmaxf(xa, xb);
        if (__all(lo >  20.0f)) mpos |= (1u << i);
        else if (__all(hi < -20.0f)) mneg |= (1u << i);
    }
    unsigned mact = 0xFFFFu & ~(mpos | mneg);

    float scores[TBT];
    if (mact == 0u){
        // -------- fast tier: all i saturated -> h_j exactly linear in t --------
        float hA[16], hB[16];
        #pragma unroll
        for (int j = 0; j < 16; j++){ hA[j] = sb2b2[j]; hB[j] = 0.0f; }
        #pragma unroll
        for (int i = 0; i < 16; i++){
            if (mpos & (1u << i)){          // wave-uniform scalar branch
                float u = u2r[i], v = v2r[i];
                #pragma unroll
                for (int j = 0; j < 16; j++){
                    float wv = sb2w2[i*16 + j];     // uniform -> s_load (SGPR)
                    hA[j] = fmaf(v, wv, hA[j]);
                    hB[j] = fmaf(u, wv, hB[j]);
                }
            }
        }
        // classify j's from endpoints (exact: h_j linear in t), fold pos-j's
        unsigned jact = 0u;
        float SA = p2bv, SB = 0.0f;
        #pragma unroll
        for (int j = 0; j < 16; j++){
            float h0 = fmaf(tv[0],     hB[j], hA[j]);
            float h7 = fmaf(tv[TBT-1], hB[j], hA[j]);
            float lo = fminf(h0, h7), hi = fmaxf(h0, h7);
            float pw = p2w[j];
            if (__all(lo > 20.0f)){
                SA = fmaf(hA[j], pw, SA);
                SB = fmaf(hB[j], pw, SB);
            } else if (!__all(hi < -20.0f)){
                jact |= (1u << j);
            }
        }
        if (jact == 0u){
            #pragma unroll
            for (int ti = 0; ti < TBT; ti++) scores[ti] = fmaf(tv[ti], SB, SA);
        } else {
            #pragma unroll
            for (int ti = 0; ti < TBT; ti++){
                float s = fmaf(tv[ti], SB, SA);
                #pragma unroll
                for (int j = 0; j < 16; j++){
                    if (jact & (1u << j))
                        s = fmaf(silu_f(fmaf(tv[ti], hB[j], hA[j])), p2w[j], s);
                }
                scores[ti] = s;
            }
        }
    } else {
        // -------- slow tier: per-pair path (tested) --------
        #pragma unroll
        for (int tp = 0; tp < TBT; tp += 2){
            float h2a[16], h2b[16];
            #pragma unroll
            for (int j = 0; j < 16; j++){ float b = sb2b2[j]; h2a[j] = b; h2b[j] = b; }
            #pragma unroll
            for (int i = 0; i < 16; i++){
                if (mneg & (1u << i)) continue;           // a == 0: skip fan-out
                float u = u2r[i], v = v2r[i];
                float aa = fmaf(tv[tp],   u, v);
                float ab = fmaf(tv[tp+1], u, v);
                if (!(mpos & (1u << i))){                 // not linear-saturated
                    aa = silu_f(aa);
                    ab = silu_f(ab);
                }
                #pragma unroll
                for (int j = 0; j < 16; j++){
                    float wv = sb2w2[i*16 + j];           // uniform -> s_load
                    h2a[j] = fmaf(aa, wv, h2a[j]);
                    h2b[j] = fmaf(ab, wv, h2b[j]);
                }
            }
            float sa = p2bv, sb = p2bv;
            #pragma unroll
            for (int j = 0; j < 16; j++){
                float pw = p2w[j];
                float ha = h2a[j], hb = h2b[j];
                if (__all(fminf(ha, hb) > 20.0f)){
                    sa = fmaf(ha, pw, sa);
                    sb = fmaf(hb, pw, sb);
                } else if (__all(fmaxf(ha, hb) < -20.0f)){
                    // silu(h) ~ 0: no contribution
                } else {
                    sa = fmaf(silu_f(ha), pw, sa);
                    sb = fmaf(silu_f(hb), pw, sb);
                }
            }
            scores[tp] = sa; scores[tp+1] = sb;
        }
    }

    float c0r[TBT], c1r[TBT];
    {
        float u10 = sb1w1[0] - sb1w1[2], u11 = sb1w1[1] - sb1w1[3];
        float w00 = sb1w2[0], w01 = sb1w2[1], w10 = sb1w2[2], w11 = sb1w2[3];
        float b0 = sb1b2[0], b1 = sb1b2[1];
        // classify gl0/gl1 over the block window (same monotone-endpoint trick)
        float x0a = fmaf(tv[0], u10, v1r0), x0b = fmaf(tv[TBT-1], u10, v1r0);
        float x1a = fmaf(tv[0], u11, v1r1), x1b = fmaf(tv[TBT-1], u11, v1r1);
        bool p0 = __all(fminf(x0a, x0b) >  20.0f);
        bool n0 = __all(fmaxf(x0a, x0b) < -20.0f);
        bool p1 = __all(fminf(x1a, x1b) >  20.0f);
        bool n1 = __all(fmaxf(x1a, x1b) < -20.0f);
        #pragma unroll
        for (int ti = 0; ti < TBT; ti++){
            float x0 = fmaf(tv[ti], u10, v1r0);
            float x1 = fmaf(tv[ti], u11, v1r1);
            float gl0, gl1;
            if (p0)      gl0 = x0;
            else if (n0) gl0 = 0.0f;
            else         gl0 = silu_f(x0);
            if (p1)      gl1 = x1;
            else if (n1) gl1 = 0.0f;
            else         gl1 = silu_f(x1);
            float y0 = fmaf(gl0, w00, fmaf(gl1, w10, b0));
            float y1 = fmaf(gl0, w01, fmaf(gl1, w11, b1));
            if (__all(fminf(y0, y1) > 20.0f)){
                c0r[ti] = y0; c1r[ti] = y1;
            } else if (__all(fmaxf(y0, y1) < -20.0f)){
                c0r[ti] = 0.0f; c1r[ti] = 0.0f;
            } else {
                c0r[ti] = silu_f(y0); c1r[ti] = silu_f(y1);
            }
        }
    }

    // ================= LDS-transpose reduce (R16, confirmed) =================
    // --- max over w for each ti ---
    #pragma unroll
    for (int ti = 0; ti < TBT; ti++) s_red[0][ti][w] = scores[ti];   // stride-1: conflict-free
    __syncthreads();
    if (wave == 0){
        int ti = lane >> 3, ch = lane & 7;
        const float4* rp = (const float4*)&s_red[0][ti][ch*32];
        float mx = -3.402823466e38f;
        #pragma unroll
        for (int oo = 0; oo < 8; oo++){
            int o = (oo + ch) & 7;        // rotation -> per-step distinct banks
            float4 v = rp[o];
            mx = fmaxf(mx, fmaxf(fmaxf(v.x, v.y), fmaxf(v.z, v.w)));
        }
        mx = fmaxf(mx, __shfl_xor(mx, 1));
        mx = fmaxf(mx, __shfl_xor(mx, 2));
        mx = fmaxf(mx, __shfl_xor(mx, 4));
        if (ch == 0) s_mx[ti] = mx;
    }
    __syncthreads();

    float e[TBT];
    #pragma unroll
    for (int ti = 0; ti < TBT; ti++){
        e[ti] = __expf(scores[ti] - s_mx[ti]);     // broadcast read: conflict-free
        s_red[0][ti][w] = e[ti];
        s_red[1][ti][w] = e[ti] * c0r[ti];
        s_red[2][ti][w] = e[ti] * c1r[ti];
    }
    __syncthreads();
    if (wave < 3){
        int ti = lane >> 3, ch = lane & 7;
        const float4* rp = (const float4*)&s_red[wave][ti][ch*32];
        float s = 0.0f;
        #pragma unroll
        for (int oo = 0; oo < 8; oo++){
            int o = (oo + ch) & 7;
            float4 v = rp[o];
            s += (v.x + v.y) + (v.z + v.w);
        }
        s += __shfl_xor(s, 1);
        s += __shfl_xor(s, 2);
        s += __shfl_xor(s, 4);
        if (ch == 0) s_sum[wave][ti] = s;
    }
    __syncthreads();

    unsigned short* wbase = wsm_b + ((size_t)n*TT + t0)*WT + w;
    #pragma unroll
    for (int ti = 0; ti < TBT; ti++){
        float rS = fast_rcp(s_sum[0][ti]);         // broadcast read
        wbase[(size_t)ti*WT] = f2bf(e[ti] * rS);
    }
    if (tid < TBT){
        int ti = tid;
        float rS = fast_rcp(s_sum[0][ti]);
        float2 wc;
        wc.x = s_sum[1][ti] * rS;
        wc.y = s_sum[2][ti] * rS;
        *(float2*)(wc_g + ((size_t)n*TT + t0 + ti)*2) = wc;
    }
}

// ---------------- Kernel C2: out_r via bf16 MFMA GEMM + epilogue (R7 form) ----------------
__global__ __launch_bounds__(512) void outr_mfma_k(
    const unsigned short* __restrict__ wsmB, const unsigned short* __restrict__ featP,
    const float* __restrict__ wc_g,
    const float* __restrict__ p1w, const float* __restrict__ p1b,
    float* __restrict__ out)
{
    int n    = blockIdx.y;
    int t0   = blockIdx.x * 32;
    int tid  = threadIdx.x;
    int lane = tid & 63, wave = tid >> 6;
    int tw   = t0 + (wave >> 2) * 16;    // waves 0-3 -> t0, 4-7 -> t0+16
    int dbase = (wave & 3) * 4;          // 4 dt-blocks (64 d) per wave
    int l15  = lane & 15, quad = lane >> 4;

    f32x4 acc[4];
    #pragma unroll
    for (int dt = 0; dt < 4; dt++) acc[dt] = (f32x4){0.f, 0.f, 0.f, 0.f};

    const unsigned short* aPtr = wsmB + ((size_t)(n*TT + tw + l15))*WT + quad*8;

    #pragma unroll
    for (int kb = 0; kb < 8; kb++){
        short8_t af = *(const short8_t*)(aPtr + kb*32);
        const unsigned short* bp = featP + ((size_t)(n*8 + kb)*DIM + dbase*16 + l15)*32 + quad*8;
        #pragma unroll
        for (int dt = 0; dt < 4; dt++){
            short8_t bf = *(const short8_t*)(bp + (size_t)dt*16*32);
            acc[dt] = __builtin_amdgcn_mfma_f32_16x16x32_bf16(af, bf, acc[dt], 0, 0, 0);
        }
    }

    float wc0[4], wc1[4];
    #pragma unroll
    for (int r = 0; r < 4; r++){
        const float* wp = wc_g + ((size_t)(n*TT + tw + quad*4 + r))*2;
        wc0[r] = wp[0]; wc1[r] = wp[1];
    }
    float* obase = out + ((size_t)(n*TT + tw + quad*4))*DIM;
    #pragma unroll
    for (int dt = 0; dt < 4; dt++){
        int d = (dbase + dt)*16 + l15;   // D col
        float pa = p1w[d], pb2 = p1w[DIM + d], pc = p1b[d];
        #pragma unroll
        for (int r = 0; r < 4; r++){     // D row = quad*4 + r
            float val = acc[dt][r] + fmaf(wc0[r], pa, fmaf(wc1[r], pb2, pc));
            obase[(size_t)r*DIM + d] = val;
        }
    }
}

// ---------------- Fallback fused kernel (R1, known-good) if ws too small ----------------
__global__ __launch_bounds__(256) void fused_k(
    const float* __restrict__ Tg, const float* __restrict__ feat,
    const float* __restrict__ v1g, const float* __restrict__ v2g,
    const float* __restrict__ sb1w1, const float* __restrict__ sb1w2, const float* __restrict__ sb1b2,
    const float* __restrict__ sb2w1, const float* __restrict__ sb2w2, const float* __restrict__ sb2b2,
    const float* __restrict__ p1w, const float* __restrict__ p1b,
    const float* __restrict__ p2w, const float* __restrict__ p2b,
    float* __restrict__ out)
{
    int n   = blockIdx.y;
    int t0  = blockIdx.x * TBT;
    int tid = threadIdx.x;
    int w   = tid;
    int lane = tid & 63, wave = tid >> 6;

    __shared__ float s_w2[16*16];
    __shared__ float s_u2[16], s_b2[16], s_p2w[16];
    __shared__ float s_u1[2], s_w21[4], s_b21[2];
    __shared__ float s_wsmT[WT][TBT];
    __shared__ float s_xa[4][TBT];
    __shared__ float s_xs[4][TBT];
    __shared__ float s_xc0[4][TBT], s_xc1[4][TBT];
    __shared__ float s_wc0[TBT], s_wc1[TBT];
    __shared__ float s_out[4][DIM];

    s_w2[tid] = sb2w2[tid];
    if (tid < 16){
        s_u2[tid]  = sb2w1[tid] - sb2w1[16 + tid];
        s_b2[tid]  = sb2b2[tid];
        s_p2w[tid] = p2w[tid];
    } else if (tid < 18){
        int p = tid - 16;
        s_u1[p]  = sb1w1[p] - sb1w1[2 + p];
        s_b21[p] = sb1b2[p];
    } else if (tid < 22){
        s_w21[tid - 18] = sb1w2[tid - 18];
    }
    __syncthreads();

    float v2r[16];
    {
        const float4* vp = (const float4*)(v2g + (size_t)(n*WT + w)*16);
        float4 a = vp[0], b = vp[1], c = vp[2], d = vp[3];
        v2r[0]=a.x; v2r[1]=a.y; v2r[2]=a.z; v2r[3]=a.w;
        v2r[4]=b.x; v2r[5]=b.y; v2r[6]=b.z; v2r[7]=b.w;
        v2r[8]=c.x; v2r[9]=c.y; v2r[10]=c.z; v2r[11]=c.w;
        v2r[12]=d.x; v2r[13]=d.y; v2r[14]=d.z; v2r[15]=d.w;
    }
    float v1r0, v1r1;
    {
        const float* vp = v1g + (size_t)(n*WT + w)*2;
        v1r0 = vp[0]; v1r1 = vp[1];
    }
    float p2bv = p2b[0];
    float tv[TBT];
    #pragma unroll
    for (int ti = 0; ti < TBT; ti++) tv[ti] = Tg[t0 + ti];

    float scores[TBT];
    #pragma unroll
    for (int tp = 0; tp < TBT; tp += 2){
        float h2a[16], h2b[16];
        #pragma unroll
        for (int j = 0; j < 16; j++){ float b = s_b2[j]; h2a[j] = b; h2b[j] = b; }
        #pragma unroll
        for (int i = 0; i < 16; i++){
            float u = s_u2[i], v = v2r[i];
            float aa = silu_f(fmaf(tv[tp],   u, v));
            float ab = silu_f(fmaf(tv[tp+1], u, v));
            #pragma unroll
            for (int j = 0; j < 16; j++){
                float wv = s_w2[i*16 + j];
                h2a[j] = fmaf(aa, wv, h2a[j]);
                h2b[j] = fmaf(ab, wv, h2b[j]);
            }
        }
        float sa = p2bv, sb = p2bv;
        #pragma unroll
        for (int j = 0; j < 16; j++){
            float pw = s_p2w[j];
            sa = fmaf(silu_f(h2a[j]), pw, sa);
            sb = fmaf(silu_f(h2b[j]), pw, sb);
        }
        scores[tp] = sa; scores[tp+1] = sb;
    }

    float c0r[TBT], c1r[TBT];
    {
        float u10 = s_u1[0], u11 = s_u1[1];
        float w00 = s_w21[0], w01 = s_w21[1], w10 = s_w21[2], w11 = s_w21[3];
        float b0 = s_b21[0], b1 = s_b21[1];
        #pragma unroll
        for (int ti = 0; ti < TBT; ti++){
            float gl0 = silu_f(fmaf(tv[ti], u10, v1r0));
            float gl1 = silu_f(fmaf(tv[ti], u11, v1r1));
            c0r[ti] = silu_f(fmaf(gl0, w00, fmaf(gl1, w10, b0)));
            c1r[ti] = silu_f(fmaf(gl0, w01, fmaf(gl1, w11, b1)));
        }
    }

    float m[TBT];
    #pragma unroll
    for (int ti = 0; ti < TBT; ti++) m[ti] = scores[ti];
    #pragma unroll
    for (int off = 32; off; off >>= 1){
        #pragma unroll
        for (int ti = 0; ti < TBT; ti++) m[ti] = fmaxf(m[ti], __shfl_xor(m[ti], off));
    }
    if (lane == 0){
        #pragma unroll
        for (int ti = 0; ti < TBT; ti++) s_xa[wave][ti] = m[ti];
    }
    __syncthreads();
    #pragma unroll
    for (int ti = 0; ti < TBT; ti++)
        m[ti] = fmaxf(fmaxf(s_xa[0][ti], s_xa[1][ti]), fmaxf(s_xa[2][ti], s_xa[3][ti]));

    float e[TBT], ps[TBT], pc0[TBT], pc1[TBT];
    #pragma unroll
    for (int ti = 0; ti < TBT; ti++){
        e[ti]  = __expf(scores[ti] - m[ti]);
        ps[ti] = e[ti];
        pc0[ti] = e[ti] * c0r[ti];
        pc1[ti] = e[ti] * c1r[ti];
    }
    #pragma unroll
    for (int off = 32; off; off >>= 1){
        #pragma unroll
        for (int ti = 0; ti < TBT; ti++){
            ps[ti]  += __shfl_xor(ps[ti],  off);
            pc0[ti] += __shfl_xor(pc0[ti], off);
            pc1[ti] += __shfl_xor(pc1[ti], off);
        }
    }
    if (lane == 0){
        #pragma unroll
        for (int ti = 0; ti < TBT; ti++){
            s_xs[wave][ti]  = ps[ti];
            s_xc0[wave][ti] = pc0[ti];
            s_xc1[wave][ti] = pc1[ti];
        }
    }
    __syncthreads();
    #pragma unroll
    for (int ti = 0; ti < TBT; ti++){
        float S  = s_xs[0][ti] + s_xs[1][ti] + s_xs[2][ti] + s_xs[3][ti];
        float rS = fast_rcp(S);
        s_wsmT[w][ti] = e[ti] * rS;
    }
    if (tid < TBT){
        int ti = tid;
        float S  = s_xs[0][ti] + s_xs[1][ti] + s_xs[2][ti] + s_xs[3][ti];
        float rS = fast_rcp(S);
        s_wc0[ti] = (s_xc0[0][ti] + s_xc0[1][ti] + s_xc0[2][ti] + s_xc0[3][ti]) * rS;
        s_wc1[ti] = (s_xc1[0][ti] + s_xc1[1][ti] + s_xc1[2][ti] + s_xc1[3][ti]) * rS;
    }
    __syncthreads();

    int wid = wave;
    int dq  = lane;
    const float* fbase = feat + (size_t)n*WT*DIM + dq*4;
    float4 acc[TBT];
    #pragma unroll
    for (int i = 0; i < TBT; i++) acc[i] = make_float4(0.f, 0.f, 0.f, 0.f);

    #pragma unroll 4
    for (int w0 = wid; w0 < WT; w0 += 4){
        float4 f = *(const float4*)(fbase + (size_t)w0*DIM);
        const float4* wp = (const float4*)&s_wsmT[w0][0];
        float4 wA = wp[0], wB = wp[1];
        fma4(acc[0], wA.x, f); fma4(acc[1], wA.y, f);
        fma4(acc[2], wA.z, f); fma4(acc[3], wA.w, f);
        fma4(acc[4], wB.x, f); fma4(acc[5], wB.y, f);
        fma4(acc[6], wB.z, f); fma4(acc[7], wB.w, f);
    }

    float pw0 = p1w[tid], pw1 = p1w[DIM + tid], pbv = p1b[tid];
    float* orow = out + ((size_t)n*TT + t0)*DIM;
    #pragma unroll
    for (int ti = 0; ti < TBT; ti++){
        __syncthreads();
        *(float4*)&s_out[wid][dq*4] = acc[ti];
        __syncthreads();
        float r = s_out[0][tid] + s_out[1][tid] + s_out[2][tid] + s_out[3][tid];
        float o = fmaf(s_wc0[ti], pw0, fmaf(s_wc1[ti], pw1, r + pbv));
        orow[(size_t)ti*DIM + tid] = o;
    }
}

extern "C" void kernel_launch(void* const* d_in, const int* in_sizes, int n_in,
                              void* d_out, int out_size, void* d_ws, size_t ws_size,
                              hipStream_t stream)
{
    const float* Tg    = (const float*)d_in[0];
    const float* dur   = (const float*)d_in[1];
    const float* feat  = (const float*)d_in[2];
    const float* c1w   = (const float*)d_in[3];
    const float* c1b   = (const float*)d_in[4];
    const float* bn1g  = (const float*)d_in[5];
    const float* bn1b  = (const float*)d_in[6];
    const float* bn1m  = (const float*)d_in[7];
    const float* bn1v  = (const float*)d_in[8];
    const float* c2w   = (const float*)d_in[9];
    const float* c2b   = (const float*)d_in[10];
    const float* bn2g  = (const float*)d_in[11];
    const float* bn2b  = (const float*)d_in[12];
    const float* bn2m  = (const float*)d_in[13];
    const float* bn2v  = (const float*)d_in[14];
    const float* sb1w1 = (const float*)d_in[15];
    const float* sb1b1 = (const float*)d_in[16];
    const float* sb1w2 = (const float*)d_in[17];
    const float* sb1b2 = (const float*)d_in[18];
    const float* sb2w1 = (const float*)d_in[19];
    const float* sb2b1 = (const float*)d_in[20];
    const float* sb2w2 = (const float*)d_in[21];
    const float* sb2b2 = (const float*)d_in[22];
    const float* p1w   = (const float*)d_in[23];
    const float* p1b   = (const float*)d_in[24];
    const float* p2w   = (const float*)d_in[25];
    const float* p2b   = (const float*)d_in[26];
    float* out = (float*)d_out;

    // ws layout (float units): v1[8192] v2[65536] wc[65536]
    // then bf16 arrays: wsmB[NN*TT*WT] featP[NN*WT*DIM]
    float* ws = (float*)d_ws;
    float* v1  = ws;
    float* v2  = ws + 8192;
    float* wc  = ws + 8192 + 65536;
    unsigned short* wsmB  = (unsigned short*)(ws + 8192 + 65536 + 65536);
    unsigned short* featP = wsmB + (size_t)NN*TT*WT;
    size_t need = ((size_t)8192 + 65536 + 65536)*sizeof(float)
                + ((size_t)NN*TT*WT + (size_t)NN*WT*DIM)*sizeof(unsigned short);

    prep_k<<<dim3(WT, NN), 256, 0, stream>>>(dur, feat, c1w, c1b, bn1g, bn1b, bn1m, bn1v,
                                             c2w, c2b, bn2g, bn2b, bn2m, bn2v,
                                             sb1w1, sb1b1, sb2w1, sb2b1, v1, v2);
    if (ws_size >= need){
        featpack_k<<<dim3(8, NN), 256, 0, stream>>>(feat, featP);
        score_k<<<dim3(TT/TBT, NN), 256, 0, stream>>>(Tg, v1, v2,
                                                      sb1w1, sb1w2, sb1b2,
                                                      sb2w1, sb2w2, sb2b2,
                                                      p2w, p2b, wsmB, wc);
        outr_mfma_k<<<dim3(TT/32, NN), 512, 0, stream>>>(wsmB, featP, wc, p1w, p1b, out);
    } else {
        fused_k<<<dim3(TT/TBT, NN), 256, 0, stream>>>(Tg, feat, v1, v2,
                                                      sb1w1, sb1w2, sb1b2,
                                                      sb2w1, sb2w2, sb2b2,
                                                      p1w, p1b, p2w, p2b, out);
    }
}

// Round 12
// 256.466 us; speedup vs baseline: 1.2192x; 1.0009x over previous
//
#include <hip/hip_runtime.h>
#include <hip/hip_bf16.h>

#define NN  16
#define WT  256
#define TT  2048
#define DIM 256
#define TBT 8      // t-values per block in score kernel
#define RSTR 260   // padded row stride (floats) for reduce LDS: spreads ti across banks

typedef __attribute__((ext_vector_type(8))) short short8_t;  // 8 bf16 (4 VGPRs)
typedef __attribute__((ext_vector_type(4))) float f32x4;     // MFMA acc

__device__ __forceinline__ float fast_rcp(float x){ return __builtin_amdgcn_rcpf(x); }

__device__ __forceinline__ float silu_f(float x){
    return x * fast_rcp(1.0f + __expf(-x));
}

__device__ __forceinline__ unsigned short f2bf(float x){
    union { float f; unsigned u; } v; v.f = x;
    unsigned r = v.u + 0x7FFFu + ((v.u >> 16) & 1u);   // round-to-nearest-even
    return (unsigned short)(r >> 16);
}

__device__ __forceinline__ void fma4(float4& a, float s, const float4& f){
    a.x = fmaf(s, f.x, a.x); a.y = fmaf(s, f.y, a.y);
    a.z = fmaf(s, f.z, a.z); a.w = fmaf(s, f.w, a.w);
}

// ------- Kernel B: cumsum (in-block scan) + conv(3,256->8)+BN+SiLU, fold into v1/v2 -------
__global__ __launch_bounds__(256) void prep_k(
    const float* __restrict__ dur, const float* __restrict__ feat,
    const float* __restrict__ c1w, const float* __restrict__ c1b,
    const float* __restrict__ g1,  const float* __restrict__ be1,
    const float* __restrict__ m1,  const float* __restrict__ vv1,
    const float* __restrict__ c2w, const float* __restrict__ c2b,
    const float* __restrict__ g2,  const float* __restrict__ be2,
    const float* __restrict__ m2,  const float* __restrict__ vv2,
    const float* __restrict__ sb1w1, const float* __restrict__ sb1b1,
    const float* __restrict__ sb2w1, const float* __restrict__ sb2b1,
    float* __restrict__ v1o, float* __restrict__ v2o)
{
    int w = blockIdx.x, n = blockIdx.y;
    int tid = threadIdx.x;              // channel c

    // ---- in-block inclusive scan of durations for this n ----
    __shared__ float sdur[WT];
    sdur[tid] = dur[n*WT + tid];
    __syncthreads();
    for (int off = 1; off < WT; off <<= 1){
        float v = (tid >= off) ? sdur[tid-off] : 0.0f;
        __syncthreads();
        sdur[tid] += v;
        __syncthreads();
    }
    float end   = sdur[w];              // broadcast read
    float start = end - dur[n*WT + w];  // uniform scalar load

    const float* fb = feat + (size_t)(n*WT)*DIM;
    float fm = (w > 0)    ? fb[(size_t)(w-1)*DIM + tid] : 0.0f;
    float f0 =              fb[(size_t) w   *DIM + tid];
    float fp = (w < WT-1) ? fb[(size_t)(w+1)*DIM + tid] : 0.0f;

    float pl[8], pr[8];
    #pragma unroll
    for (int o = 0; o < 8; o++){
        const float* wp = c1w + (size_t)(o*DIM + tid)*3;
        pl[o] = fmaf(fm, wp[0], fmaf(f0, wp[1], fp*wp[2]));
        const float* wq = c2w + (size_t)(o*DIM + tid)*3;
        pr[o] = fmaf(fm, wq[0], fmaf(f0, wq[1], fp*wq[2]));
    }
    #pragma unroll
    for (int o = 0; o < 8; o++){
        #pragma unroll
        for (int off = 32; off; off >>= 1){
            pl[o] += __shfl_xor(pl[o], off);
            pr[o] += __shfl_xor(pr[o], off);
        }
    }
    __shared__ float sws[4][16];
    int wave = tid >> 6, lane = tid & 63;
    if (lane == 0){
        #pragma unroll
        for (int o = 0; o < 8; o++){ sws[wave][o] = pl[o]; sws[wave][8+o] = pr[o]; }
    }
    __syncthreads();
    __shared__ float slr[16];   // [0..7]=left(SiLU'd), [8..15]=right
    if (tid < 16){
        float s = sws[0][tid] + sws[1][tid] + sws[2][tid] + sws[3][tid];
        int o = tid & 7; bool isr = tid >= 8;
        float bias = isr ? c2b[o] : c1b[o];
        float mm   = isr ? m2[o]  : m1[o];
        float vv   = isr ? vv2[o] : vv1[o];
        float gg   = isr ? g2[o]  : g1[o];
        float bb   = isr ? be2[o] : be1[o];
        float y = s + bias;
        y = (y - mm) * rsqrtf(vv + 1e-5f);
        y = y * gg + bb;
        slr[tid] = silu_f(y);
    }
    __syncthreads();
    if (tid < 16){
        int j = tid;
        float acc = sb2b1[j] - start*sb2w1[j] + end*sb2w1[16 + j];
        #pragma unroll
        for (int o = 0; o < 8; o++) acc = fmaf(slr[8+o], sb2w1[(2+o)*16 + j], acc);
        v2o[(size_t)(n*WT + w)*16 + j] = acc;
    } else if (tid < 18){
        int p = tid - 16;
        float acc = sb1b1[p] - start*sb1w1[p] + end*sb1w1[2 + p];
        #pragma unroll
        for (int o = 0; o < 8; o++) acc = fmaf(slr[o], sb1w1[(2+o)*2 + p], acc);
        v1o[(size_t)(n*WT + w)*2 + p] = acc;
    }
}

// ------- Kernel B2: pack feat into B-fragment bf16 layout [n][w/32][d][w%32] -------
__global__ __launch_bounds__(256) void featpack_k(const float* __restrict__ feat,
                                                  unsigned short* __restrict__ featP)
{
    int kb = blockIdx.x, n = blockIdx.y;   // kb = 0..7 (k-block of 32 w's)
    int d = threadIdx.x;
    const float* fb = feat + (size_t)n*WT*DIM + (size_t)kb*32*DIM + d;
    unsigned short* op = featP + ((size_t)(n*8 + kb)*DIM + d)*32;
    unsigned short buf[32];
    #pragma unroll
    for (int e = 0; e < 32; e++) buf[e] = f2bf(fb[(size_t)e*DIM]);   // coalesced reads
    #pragma unroll
    for (int g = 0; g < 4; g++){
        uint4 u;
        u.x = (unsigned)buf[g*8+0] | ((unsigned)buf[g*8+1] << 16);
        u.y = (unsigned)buf[g*8+2] | ((unsigned)buf[g*8+3] << 16);
        u.z = (unsigned)buf[g*8+4] | ((unsigned)buf[g*8+5] << 16);
        u.w = (unsigned)buf[g*8+6] | ((unsigned)buf[g*8+7] << 16);
        *(uint4*)(op + g*8) = u;
    }
}

// ---------------- Kernel C1: scores -> softmax weights (bf16, to global ws) ----------------
// R18 = R17 (scalar weights + LDS-transpose reduce, both confirmed) + RECIPROCAL-
// STORE: the normalization recomputed fast_rcp(s_sum[0][ti]) PER THREAD (8 trans
// ops x 256 threads + 8 in the wc writer, all of a block-uniform value).  The
// reduce wave now stores rcp(sum) directly; all threads just multiply.
// Bit-identical numerics (same rcp of the same value, computed once).
__global__ __launch_bounds__(256) void score_k(
    const float* __restrict__ Tg,
    const float* __restrict__ v1g, const float* __restrict__ v2g,
    const float* __restrict__ sb1w1, const float* __restrict__ sb1w2, const float* __restrict__ sb1b2,
    const float* __restrict__ sb2w1, const float* __restrict__ sb2w2, const float* __restrict__ sb2b2,
    const float* __restrict__ p2w, const float* __restrict__ p2b,
    unsigned short* __restrict__ wsm_b, float* __restrict__ wc_g)
{
    int n   = blockIdx.y;
    int t0  = blockIdx.x * TBT;
    int tid = threadIdx.x;
    int w   = tid;
    int lane = tid & 63, wave = tid >> 6;

    __shared__ __align__(16) float s_red[3][TBT][RSTR];   // 24.4 KB reduce scratch
    __shared__ float s_sum[3][TBT];    // [0] holds RECIPROCAL of sum; [1],[2] raw
    __shared__ float s_mx[TBT];

    float v2r[16];
    {
        const float4* vp = (const float4*)(v2g + (size_t)(n*WT + w)*16);
        float4 a = vp[0], b = vp[1], c = vp[2], d = vp[3];
        v2r[0]=a.x; v2r[1]=a.y; v2r[2]=a.z; v2r[3]=a.w;
        v2r[4]=b.x; v2r[5]=b.y; v2r[6]=b.z; v2r[7]=b.w;
        v2r[8]=c.x; v2r[9]=c.y; v2r[10]=c.z; v2r[11]=c.w;
        v2r[12]=d.x; v2r[13]=d.y; v2r[14]=d.z; v2r[15]=d.w;
    }
    float v1r0, v1r1;
    {
        const float* vp = v1g + (size_t)(n*WT + w)*2;
        v1r0 = vp[0]; v1r1 = vp[1];
    }
    float p2bv = p2b[0];
    float tv[TBT];
    #pragma unroll
    for (int ti = 0; ti < TBT; ti++) tv[ti] = Tg[t0 + ti];

    // uniform u_i (scalar ALU; computed once)
    float u2r[16];
    #pragma unroll
    for (int i = 0; i < 16; i++) u2r[i] = sb2w1[i] - sb2w1[16 + i];

    // ---- classify saturation of each a_i over this block's t-window ----
    unsigned mpos = 0u, mneg = 0u;
    #pragma unroll
    for (int i = 0; i < 16; i++){
        float u = u2r[i], v = v2r[i];
        float xa = fmaf(tv[0],     u, v);
        float xb = fmaf(tv[TBT-1], u, v);
        float lo = fminf(xa, xb), hi = fmaxf(xa, xb);
        if (__all(lo >  20.0f)) mpos |= (1u << i);
        else if (__all(hi < -20.0f)) mneg |= (1u << i);
    }
    unsigned mact = 0xFFFFu & ~(mpos | mneg);

    float scores[TBT];
    if (mact == 0u){
        // -------- fast tier: all i saturated -> h_j exactly linear in t --------
        float hA[16], hB[16];
        #pragma unroll
        for (int j = 0; j < 16; j++){ hA[j] = sb2b2[j]; hB[j] = 0.0f; }
        #pragma unroll
        for (int i = 0; i < 16; i++){
            if (mpos & (1u << i)){          // wave-uniform scalar branch
                float u = u2r[i], v = v2r[i];
                #pragma unroll
                for (int j = 0; j < 16; j++){
                    float wv = sb2w2[i*16 + j];     // uniform -> s_load (SGPR)
                    hA[j] = fmaf(v, wv, hA[j]);
                    hB[j] = fmaf(u, wv, hB[j]);
                }
            }
        }
        // classify j's from endpoints (exact: h_j linear in t), fold pos-j's
        unsigned jact = 0u;
        float SA = p2bv, SB = 0.0f;
        #pragma unroll
        for (int j = 0; j < 16; j++){
            float h0 = fmaf(tv[0],     hB[j], hA[j]);
            float h7 = fmaf(tv[TBT-1], hB[j], hA[j]);
            float lo = fminf(h0, h7), hi = fmaxf(h0, h7);
            float pw = p2w[j];
            if (__all(lo > 20.0f)){
                SA = fmaf(hA[j], pw, SA);
                SB = fmaf(hB[j], pw, SB);
            } else if (!__all(hi < -20.0f)){
                jact |= (1u << j);
            }
        }
        if (jact == 0u){
            #pragma unroll
            for (int ti = 0; ti < TBT; ti++) scores[ti] = fmaf(tv[ti], SB, SA);
        } else {
            #pragma unroll
            for (int ti = 0; ti < TBT; ti++){
                float s = fmaf(tv[ti], SB, SA);
                #pragma unroll
                for (int j = 0; j < 16; j++){
                    if (jact & (1u << j))
                        s = fmaf(silu_f(fmaf(tv[ti], hB[j], hA[j])), p2w[j], s);
                }
                scores[ti] = s;
            }
        }
    } else {
        // -------- slow tier: per-pair path (tested) --------
        #pragma unroll
        for (int tp = 0; tp < TBT; tp += 2){
            float h2a[16], h2b[16];
            #pragma unroll
            for (int j = 0; j < 16; j++){ float b = sb2b2[j]; h2a[j] = b; h2b[j] = b; }
            #pragma unroll
            for (int i = 0; i < 16; i++){
                if (mneg & (1u << i)) continue;           // a == 0: skip fan-out
                float u = u2r[i], v = v2r[i];
                float aa = fmaf(tv[tp],   u, v);
                float ab = fmaf(tv[tp+1], u, v);
                if (!(mpos & (1u << i))){                 // not linear-saturated
                    aa = silu_f(aa);
                    ab = silu_f(ab);
                }
                #pragma unroll
                for (int j = 0; j < 16; j++){
                    float wv = sb2w2[i*16 + j];           // uniform -> s_load
                    h2a[j] = fmaf(aa, wv, h2a[j]);
                    h2b[j] = fmaf(ab, wv, h2b[j]);
                }
            }
            float sa = p2bv, sb = p2bv;
            #pragma unroll
            for (int j = 0; j < 16; j++){
                float pw = p2w[j];
                float ha = h2a[j], hb = h2b[j];
                if (__all(fminf(ha, hb) > 20.0f)){
                    sa = fmaf(ha, pw, sa);
                    sb = fmaf(hb, pw, sb);
                } else if (__all(fmaxf(ha, hb) < -20.0f)){
                    // silu(h) ~ 0: no contribution
                } else {
                    sa = fmaf(silu_f(ha), pw, sa);
                    sb = fmaf(silu_f(hb), pw, sb);
                }
            }
            scores[tp] = sa; scores[tp+1] = sb;
        }
    }

    float c0r[TBT], c1r[TBT];
    {
        float u10 = sb1w1[0] - sb1w1[2], u11 = sb1w1[1] - sb1w1[3];
        float w00 = sb1w2[0], w01 = sb1w2[1], w10 = sb1w2[2], w11 = sb1w2[3];
        float b0 = sb1b2[0], b1 = sb1b2[1];
        // classify gl0/gl1 over the block window (same monotone-endpoint trick)
        float x0a = fmaf(tv[0], u10, v1r0), x0b = fmaf(tv[TBT-1], u10, v1r0);
        float x1a = fmaf(tv[0], u11, v1r1), x1b = fmaf(tv[TBT-1], u11, v1r1);
        bool p0 = __all(fminf(x0a, x0b) >  20.0f);
        bool n0 = __all(fmaxf(x0a, x0b) < -20.0f);
        bool p1 = __all(fminf(x1a, x1b) >  20.0f);
        bool n1 = __all(fmaxf(x1a, x1b) < -20.0f);
        #pragma unroll
        for (int ti = 0; ti < TBT; ti++){
            float x0 = fmaf(tv[ti], u10, v1r0);
            float x1 = fmaf(tv[ti], u11, v1r1);
            float gl0, gl1;
            if (p0)      gl0 = x0;
            else if (n0) gl0 = 0.0f;
            else         gl0 = silu_f(x0);
            if (p1)      gl1 = x1;
            else if (n1) gl1 = 0.0f;
            else         gl1 = silu_f(x1);
            float y0 = fmaf(gl0, w00, fmaf(gl1, w10, b0));
            float y1 = fmaf(gl0, w01, fmaf(gl1, w11, b1));
            if (__all(fminf(y0, y1) > 20.0f)){
                c0r[ti] = y0; c1r[ti] = y1;
            } else if (__all(fmaxf(y0, y1) < -20.0f)){
                c0r[ti] = 0.0f; c1r[ti] = 0.0f;
            } else {
                c0r[ti] = silu_f(y0); c1r[ti] = silu_f(y1);
            }
        }
    }

    // ================= LDS-transpose reduce (R16/R17, confirmed) =================
    // --- max over w for each ti ---
    #pragma unroll
    for (int ti = 0; ti < TBT; ti++) s_red[0][ti][w] = scores[ti];   // stride-1: conflict-free
    __syncthreads();
    if (wave == 0){
        int ti = lane >> 3, ch = lane & 7;
        const float4* rp = (const float4*)&s_red[0][ti][ch*32];
        float mx = -3.402823466e38f;
        #pragma unroll
        for (int oo = 0; oo < 8; oo++){
            int o = (oo + ch) & 7;        // rotation -> per-step distinct banks
            float4 v = rp[o];
            mx = fmaxf(mx, fmaxf(fmaxf(v.x, v.y), fmaxf(v.z, v.w)));
        }
        mx = fmaxf(mx, __shfl_xor(mx, 1));
        mx = fmaxf(mx, __shfl_xor(mx, 2));
        mx = fmaxf(mx, __shfl_xor(mx, 4));
        if (ch == 0) s_mx[ti] = mx;
    }
    __syncthreads();

    float e[TBT];
    #pragma unroll
    for (int ti = 0; ti < TBT; ti++){
        e[ti] = __expf(scores[ti] - s_mx[ti]);     // broadcast read: conflict-free
        s_red[0][ti][w] = e[ti];
        s_red[1][ti][w] = e[ti] * c0r[ti];
        s_red[2][ti][w] = e[ti] * c1r[ti];
    }
    __syncthreads();
    if (wave < 3){
        int ti = lane >> 3, ch = lane & 7;
        const float4* rp = (const float4*)&s_red[wave][ti][ch*32];
        float s = 0.0f;
        #pragma unroll
        for (int oo = 0; oo < 8; oo++){
            int o = (oo + ch) & 7;
            float4 v = rp[o];
            s += (v.x + v.y) + (v.z + v.w);
        }
        s += __shfl_xor(s, 1);
        s += __shfl_xor(s, 2);
        s += __shfl_xor(s, 4);
        if (ch == 0){
            if (wave == 0) s_sum[0][ti] = fast_rcp(s);   // store RECIPROCAL once
            else           s_sum[wave][ti] = s;
        }
    }
    __syncthreads();

    unsigned short* wbase = wsm_b + ((size_t)n*TT + t0)*WT + w;
    #pragma unroll
    for (int ti = 0; ti < TBT; ti++){
        float rS = s_sum[0][ti];                   // broadcast read (already 1/S)
        wbase[(size_t)ti*WT] = f2bf(e[ti] * rS);
    }
    if (tid < TBT){
        int ti = tid;
        float rS = s_sum[0][ti];
        float2 wc;
        wc.x = s_sum[1][ti] * rS;
        wc.y = s_sum[2][ti] * rS;
        *(float2*)(wc_g + ((size_t)n*TT + t0 + ti)*2) = wc;
    }
}

// ---------------- Kernel C2: out_r via bf16 MFMA GEMM + epilogue (R7 form) ----------------
__global__ __launch_bounds__(512) void outr_mfma_k(
    const unsigned short* __restrict__ wsmB, const unsigned short* __restrict__ featP,
    const float* __restrict__ wc_g,
    const float* __restrict__ p1w, const float* __restrict__ p1b,
    float* __restrict__ out)
{
    int n    = blockIdx.y;
    int t0   = blockIdx.x * 32;
    int tid  = threadIdx.x;
    int lane = tid & 63, wave = tid >> 6;
    int tw   = t0 + (wave >> 2) * 16;    // waves 0-3 -> t0, 4-7 -> t0+16
    int dbase = (wave & 3) * 4;          // 4 dt-blocks (64 d) per wave
    int l15  = lane & 15, quad = lane >> 4;

    f32x4 acc[4];
    #pragma unroll
    for (int dt = 0; dt < 4; dt++) acc[dt] = (f32x4){0.f, 0.f, 0.f, 0.f};

    const unsigned short* aPtr = wsmB + ((size_t)(n*TT + tw + l15))*WT + quad*8;

    #pragma unroll
    for (int kb = 0; kb < 8; kb++){
        short8_t af = *(const short8_t*)(aPtr + kb*32);
        const unsigned short* bp = featP + ((size_t)(n*8 + kb)*DIM + dbase*16 + l15)*32 + quad*8;
        #pragma unroll
        for (int dt = 0; dt < 4; dt++){
            short8_t bf = *(const short8_t*)(bp + (size_t)dt*16*32);
            acc[dt] = __builtin_amdgcn_mfma_f32_16x16x32_bf16(af, bf, acc[dt], 0, 0, 0);
        }
    }

    float wc0[4], wc1[4];
    #pragma unroll
    for (int r = 0; r < 4; r++){
        const float* wp = wc_g + ((size_t)(n*TT + tw + quad*4 + r))*2;
        wc0[r] = wp[0]; wc1[r] = wp[1];
    }
    float* obase = out + ((size_t)(n*TT + tw + quad*4))*DIM;
    #pragma unroll
    for (int dt = 0; dt < 4; dt++){
        int d = (dbase + dt)*16 + l15;   // D col
        float pa = p1w[d], pb2 = p1w[DIM + d], pc = p1b[d];
        #pragma unroll
        for (int r = 0; r < 4; r++){     // D row = quad*4 + r
            float val = acc[dt][r] + fmaf(wc0[r], pa, fmaf(wc1[r], pb2, pc));
            obase[(size_t)r*DIM + d] = val;
        }
    }
}

// ---------------- Fallback fused kernel (R1, known-good) if ws too small ----------------
__global__ __launch_bounds__(256) void fused_k(
    const float* __restrict__ Tg, const float* __restrict__ feat,
    const float* __restrict__ v1g, const float* __restrict__ v2g,
    const float* __restrict__ sb1w1, const float* __restrict__ sb1w2, const float* __restrict__ sb1b2,
    const float* __restrict__ sb2w1, const float* __restrict__ sb2w2, const float* __restrict__ sb2b2,
    const float* __restrict__ p1w, const float* __restrict__ p1b,
    const float* __restrict__ p2w, const float* __restrict__ p2b,
    float* __restrict__ out)
{
    int n   = blockIdx.y;
    int t0  = blockIdx.x * TBT;
    int tid = threadIdx.x;
    int w   = tid;
    int lane = tid & 63, wave = tid >> 6;

    __shared__ float s_w2[16*16];
    __shared__ float s_u2[16], s_b2[16], s_p2w[16];
    __shared__ float s_u1[2], s_w21[4], s_b21[2];
    __shared__ float s_wsmT[WT][TBT];
    __shared__ float s_xa[4][TBT];
    __shared__ float s_xs[4][TBT];
    __shared__ float s_xc0[4][TBT], s_xc1[4][TBT];
    __shared__ float s_wc0[TBT], s_wc1[TBT];
    __shared__ float s_out[4][DIM];

    s_w2[tid] = sb2w2[tid];
    if (tid < 16){
        s_u2[tid]  = sb2w1[tid] - sb2w1[16 + tid];
        s_b2[tid]  = sb2b2[tid];
        s_p2w[tid] = p2w[tid];
    } else if (tid < 18){
        int p = tid - 16;
        s_u1[p]  = sb1w1[p] - sb1w1[2 + p];
        s_b21[p] = sb1b2[p];
    } else if (tid < 22){
        s_w21[tid - 18] = sb1w2[tid - 18];
    }
    __syncthreads();

    float v2r[16];
    {
        const float4* vp = (const float4*)(v2g + (size_t)(n*WT + w)*16);
        float4 a = vp[0], b = vp[1], c = vp[2], d = vp[3];
        v2r[0]=a.x; v2r[1]=a.y; v2r[2]=a.z; v2r[3]=a.w;
        v2r[4]=b.x; v2r[5]=b.y; v2r[6]=b.z; v2r[7]=b.w;
        v2r[8]=c.x; v2r[9]=c.y; v2r[10]=c.z; v2r[11]=c.w;
        v2r[12]=d.x; v2r[13]=d.y; v2r[14]=d.z; v2r[15]=d.w;
    }
    float v1r0, v1r1;
    {
        const float* vp = v1g + (size_t)(n*WT + w)*2;
        v1r0 = vp[0]; v1r1 = vp[1];
    }
    float p2bv = p2b[0];
    float tv[TBT];
    #pragma unroll
    for (int ti = 0; ti < TBT; ti++) tv[ti] = Tg[t0 + ti];

    float scores[TBT];
    #pragma unroll
    for (int tp = 0; tp < TBT; tp += 2){
        float h2a[16], h2b[16];
        #pragma unroll
        for (int j = 0; j < 16; j++){ float b = s_b2[j]; h2a[j] = b; h2b[j] = b; }
        #pragma unroll
        for (int i = 0; i < 16; i++){
            float u = s_u2[i], v = v2r[i];
            float aa = silu_f(fmaf(tv[tp],   u, v));
            float ab = silu_f(fmaf(tv[tp+1], u, v));
            #pragma unroll
            for (int j = 0; j < 16; j++){
                float wv = s_w2[i*16 + j];
                h2a[j] = fmaf(aa, wv, h2a[j]);
                h2b[j] = fmaf(ab, wv, h2b[j]);
            }
        }
        float sa = p2bv, sb = p2bv;
        #pragma unroll
        for (int j = 0; j < 16; j++){
            float pw = s_p2w[j];
            sa = fmaf(silu_f(h2a[j]), pw, sa);
            sb = fmaf(silu_f(h2b[j]), pw, sb);
        }
        scores[tp] = sa; scores[tp+1] = sb;
    }

    float c0r[TBT], c1r[TBT];
    {
        float u10 = s_u1[0], u11 = s_u1[1];
        float w00 = s_w21[0], w01 = s_w21[1], w10 = s_w21[2], w11 = s_w21[3];
        float b0 = s_b21[0], b1 = s_b21[1];
        #pragma unroll
        for (int ti = 0; ti < TBT; ti++){
            float gl0 = silu_f(fmaf(tv[ti], u10, v1r0));
            float gl1 = silu_f(fmaf(tv[ti], u11, v1r1));
            c0r[ti] = silu_f(fmaf(gl0, w00, fmaf(gl1, w10, b0)));
            c1r[ti] = silu_f(fmaf(gl0, w01, fmaf(gl1, w11, b1)));
        }
    }

    float m[TBT];
    #pragma unroll
    for (int ti = 0; ti < TBT; ti++) m[ti] = scores[ti];
    #pragma unroll
    for (int off = 32; off; off >>= 1){
        #pragma unroll
        for (int ti = 0; ti < TBT; ti++) m[ti] = fmaxf(m[ti], __shfl_xor(m[ti], off));
    }
    if (lane == 0){
        #pragma unroll
        for (int ti = 0; ti < TBT; ti++) s_xa[wave][ti] = m[ti];
    }
    __syncthreads();
    #pragma unroll
    for (int ti = 0; ti < TBT; ti++)
        m[ti] = fmaxf(fmaxf(s_xa[0][ti], s_xa[1][ti]), fmaxf(s_xa[2][ti], s_xa[3][ti]));

    float e[TBT], ps[TBT], pc0[TBT], pc1[TBT];
    #pragma unroll
    for (int ti = 0; ti < TBT; ti++){
        e[ti]  = __expf(scores[ti] - m[ti]);
        ps[ti] = e[ti];
        pc0[ti] = e[ti] * c0r[ti];
        pc1[ti] = e[ti] * c1r[ti];
    }
    #pragma unroll
    for (int off = 32; off; off >>= 1){
        #pragma unroll
        for (int ti = 0; ti < TBT; ti++){
            ps[ti]  += __shfl_xor(ps[ti],  off);
            pc0[ti] += __shfl_xor(pc0[ti], off);
            pc1[ti] += __shfl_xor(pc1[ti], off);
        }
    }
    if (lane == 0){
        #pragma unroll
        for (int ti = 0; ti < TBT; ti++){
            s_xs[wave][ti]  = ps[ti];
            s_xc0[wave][ti] = pc0[ti];
            s_xc1[wave][ti] = pc1[ti];
        }
    }
    __syncthreads();
    #pragma unroll
    for (int ti = 0; ti < TBT; ti++){
        float S  = s_xs[0][ti] + s_xs[1][ti] + s_xs[2][ti] + s_xs[3][ti];
        float rS = fast_rcp(S);
        s_wsmT[w][ti] = e[ti] * rS;
    }
    if (tid < TBT){
        int ti = tid;
        float S  = s_xs[0][ti] + s_xs[1][ti] + s_xs[2][ti] + s_xs[3][ti];
        float rS = fast_rcp(S);
        s_wc0[ti] = (s_xc0[0][ti] + s_xc0[1][ti] + s_xc0[2][ti] + s_xc0[3][ti]) * rS;
        s_wc1[ti] = (s_xc1[0][ti] + s_xc1[1][ti] + s_xc1[2][ti] + s_xc1[3][ti]) * rS;
    }
    __syncthreads();

    int wid = wave;
    int dq  = lane;
    const float* fbase = feat + (size_t)n*WT*DIM + dq*4;
    float4 acc[TBT];
    #pragma unroll
    for (int i = 0; i < TBT; i++) acc[i] = make_float4(0.f, 0.f, 0.f, 0.f);

    #pragma unroll 4
    for (int w0 = wid; w0 < WT; w0 += 4){
        float4 f = *(const float4*)(fbase + (size_t)w0*DIM);
        const float4* wp = (const float4*)&s_wsmT[w0][0];
        float4 wA = wp[0], wB = wp[1];
        fma4(acc[0], wA.x, f); fma4(acc[1], wA.y, f);
        fma4(acc[2], wA.z, f); fma4(acc[3], wA.w, f);
        fma4(acc[4], wB.x, f); fma4(acc[5], wB.y, f);
        fma4(acc[6], wB.z, f); fma4(acc[7], wB.w, f);
    }

    float pw0 = p1w[tid], pw1 = p1w[DIM + tid], pbv = p1b[tid];
    float* orow = out + ((size_t)n*TT + t0)*DIM;
    #pragma unroll
    for (int ti = 0; ti < TBT; ti++){
        __syncthreads();
        *(float4*)&s_out[wid][dq*4] = acc[ti];
        __syncthreads();
        float r = s_out[0][tid] + s_out[1][tid] + s_out[2][tid] + s_out[3][tid];
        float o = fmaf(s_wc0[ti], pw0, fmaf(s_wc1[ti], pw1, r + pbv));
        orow[(size_t)ti*DIM + tid] = o;
    }
}

extern "C" void kernel_launch(void* const* d_in, const int* in_sizes, int n_in,
                              void* d_out, int out_size, void* d_ws, size_t ws_size,
                              hipStream_t stream)
{
    const float* Tg    = (const float*)d_in[0];
    const float* dur   = (const float*)d_in[1];
    const float* feat  = (const float*)d_in[2];
    const float* c1w   = (const float*)d_in[3];
    const float* c1b   = (const float*)d_in[4];
    const float* bn1g  = (const float*)d_in[5];
    const float* bn1b  = (const float*)d_in[6];
    const float* bn1m  = (const float*)d_in[7];
    const float* bn1v  = (const float*)d_in[8];
    const float* c2w   = (const float*)d_in[9];
    const float* c2b   = (const float*)d_in[10];
    const float* bn2g  = (const float*)d_in[11];
    const float* bn2b  = (const float*)d_in[12];
    const float* bn2m  = (const float*)d_in[13];
    const float* bn2v  = (const float*)d_in[14];
    const float* sb1w1 = (const float*)d_in[15];
    const float* sb1b1 = (const float*)d_in[16];
    const float* sb1w2 = (const float*)d_in[17];
    const float* sb1b2 = (const float*)d_in[18];
    const float* sb2w1 = (const float*)d_in[19];
    const float* sb2b1 = (const float*)d_in[20];
    const float* sb2w2 = (const float*)d_in[21];
    const float* sb2b2 = (const float*)d_in[22];
    const float* p1w   = (const float*)d_in[23];
    const float* p1b   = (const float*)d_in[24];
    const float* p2w   = (const float*)d_in[25];
    const float* p2b   = (const float*)d_in[26];
    float* out = (float*)d_out;

    // ws layout (float units): v1[8192] v2[65536] wc[65536]
    // then bf16 arrays: wsmB[NN*TT*WT] featP[NN*WT*DIM]
    float* ws = (float*)d_ws;
    float* v1  = ws;
    float* v2  = ws + 8192;
    float* wc  = ws + 8192 + 65536;
    unsigned short* wsmB  = (unsigned short*)(ws + 8192 + 65536 + 65536);
    unsigned short* featP = wsmB + (size_t)NN*TT*WT;
    size_t need = ((size_t)8192 + 65536 + 65536)*sizeof(float)
                + ((size_t)NN*TT*WT + (size_t)NN*WT*DIM)*sizeof(unsigned short);

    prep_k<<<dim3(WT, NN), 256, 0, stream>>>(dur, feat, c1w, c1b, bn1g, bn1b, bn1m, bn1v,
                                             c2w, c2b, bn2g, bn2b, bn2m, bn2v,
                                             sb1w1, sb1b1, sb2w1, sb2b1, v1, v2);
    if (ws_size >= need){
        featpack_k<<<dim3(8, NN), 256, 0, stream>>>(feat, featP);
        score_k<<<dim3(TT/TBT, NN), 256, 0, stream>>>(Tg, v1, v2,
                                                      sb1w1, sb1w2, sb1b2,
                                                      sb2w1, sb2w2, sb2b2,
                                                      p2w, p2b, wsmB, wc);
        outr_mfma_k<<<dim3(TT/32, NN), 512, 0, stream>>>(wsmB, featP, wc, p1w, p1b, out);
    } else {
        fused_k<<<dim3(TT/TBT, NN), 256, 0, stream>>>(Tg, feat, v1, v2,
                                                      sb1w1, sb1w2, sb1b2,
                                                      sb2w1, sb2w2, sb2b2,
                                                      p1w, p1b, p2w, p2b, out);
    }
}